// Round 11
// baseline (240.569 us; speedup 1.0000x reference)
//
#include <hip/hip_runtime.h>
#include <math.h>
#include <stdint.h>

// GraphTransformerLayer on MI355X (gfx950).
// B=8, N=1024, D=512, H=8, Dh=64, F=2048.
// Round 11: attn_ctx -> triple-buffered staging + raw s_barrier with COUNTED
//           vmcnt (T3/T4; never vmcnt(0) in steady loop), full 16-tile unroll;
//           permuted eadj table (4 vec loads/tile); -C folded into MFMA C-in.

using bf16_t = __bf16;
typedef __attribute__((__ext_vector_type__(8))) __bf16 bf16x8;
typedef __attribute__((__ext_vector_type__(4))) __bf16 bf16x4;
typedef __attribute__((__ext_vector_type__(4))) float  f32x4;

#define DEVI __device__ __forceinline__

DEVI f32x4 mfma16(bf16x8 a, bf16x8 b, f32x4 c) {
  return __builtin_amdgcn_mfma_f32_16x16x32_bf16(a, b, c, 0, 0, 0);
}

// async global->LDS, 16B per lane. dest = wave-uniform base (+ lane*16 by HW).
DEVI void gload_lds16(const void* g, void* l) {
  __builtin_amdgcn_global_load_lds(
      (const __attribute__((address_space(1))) uint32_t*)g,
      (__attribute__((address_space(3))) uint32_t*)l, 16, 0, 0);
}

#define EPSC  (1e-5f)
#define QSCALE 0.18033688f   // 0.125 * log2(e): scores come out of MFMA in base-2

// ---------------- fused converts: x (4096) + weights (3072) + eadj prep (256) ----------------
// eadj is stored PERMUTED within each 64-col group: pos = (c&15)*4 + ((c>>4)&3)
// so that ctx lane l16 reads cols {l16, 16+l16, 32+l16, 48+l16} as one bf16x4.
__global__ __launch_bounds__(256) void k_cvtall(const float* __restrict__ x,
                                                const float* __restrict__ wq,
                                                const float* __restrict__ wk,
                                                const float* __restrict__ wv,
                                                const float* __restrict__ wo,
                                                const float* __restrict__ w1,
                                                const float* __restrict__ w2,
                                                const float* __restrict__ adj,
                                                const int* __restrict__ msk,
                                                bf16_t* __restrict__ ox,
                                                bf16_t* __restrict__ owq,
                                                bf16_t* __restrict__ owk,
                                                bf16_t* __restrict__ owv,
                                                bf16_t* __restrict__ owo,
                                                bf16_t* __restrict__ ow1,
                                                bf16_t* __restrict__ ow2,
                                                bf16_t* __restrict__ eadjP) {
  int blk = blockIdx.x;
  if (blk >= 7168) {  // eadj prep: 256 blocks x 4 rows
    int row  = (blk - 7168) * 4 + (threadIdx.x >> 6);
    int lane = threadIdx.x & 63;
    for (int i = 0; i < 16; i++) {
      int c = lane + 64 * i;
      size_t idx = (size_t)row * 1024 + c;
      float a = adj[idx];
      bool valid = (msk[idx] != 0);
      int pos = (c & ~63) + ((c & 15) << 2) + ((c >> 4) & 3);
      eadjP[(size_t)row * 1024 + pos] = valid ? (__bf16)__expf(a) : (__bf16)0.f;
    }
    return;
  }
  const float* src; bf16_t* dst; int base;
  if (blk < 4096)      { src = x;  dst = ox;  base = blk; }
  else {
    blk -= 4096;
    if      (blk < 256)  { src = wq; dst = owq; base = blk; }
    else if (blk < 512)  { src = wk; dst = owk; base = blk - 256; }
    else if (blk < 768)  { src = wv; dst = owv; base = blk - 512; }
    else if (blk < 1024) { src = wo; dst = owo; base = blk - 768; }
    else if (blk < 2048) { src = w1; dst = ow1; base = blk - 1024; }
    else                 { src = w2; dst = ow2; base = blk - 2048; }
  }
  int i = base * 256 + threadIdx.x;
  float4 v = ((const float4*)src)[i];
  bf16x4 o = { (__bf16)v.x, (__bf16)v.y, (__bf16)v.z, (__bf16)v.w };
  ((bf16x4*)dst)[i] = o;
}

// ---------------- tiled GEMM: C[8192 x N] = A[8192 x K] @ B[N x K]^T ----------------
// 128x128 tile, 4 waves (2x2), each wave 64x64 (4x4 fragments). BK=32.
// NSPLIT>1: K split into NSPLIT slices; slice s writes outf + s*8192*out_ncols.
template<int EPI, int NSPLIT>
__global__ __launch_bounds__(256) void k_gemm(const bf16_t* __restrict__ A,
                                              const bf16_t* __restrict__ B,
                                              int K, int nbx,
                                              const float* __restrict__ bias,
                                              bf16_t* __restrict__ outb,
                                              float* __restrict__ outf,
                                              int out_ncols) {
  __shared__ bf16_t lA[2][4096];
  __shared__ bf16_t lB[2][4096];
  int bid = blockIdx.x;
  int bps = 64 * nbx;                 // blocks per split (M/128 = 64)
  int split = bid / bps, r = bid - split * bps;
  int nb = r % nbx, mb = r / nbx;
  int KS = K / NSPLIT;
  const bf16_t* Ab = A + (size_t)split * KS;
  const bf16_t* Bb = B + (size_t)split * KS;
  int tid = threadIdx.x, wid = tid >> 6, lane = tid & 63;
  int l16 = lane & 15, g = lane >> 4;
  int wr = wid >> 1, wc = wid & 1;
  int rowbase = mb * 128, c0 = nb * 128;

  int dA0 = wid * 2048 + lane * 16;
  int rA0 = dA0 >> 6;
  int cbA = ((dA0 >> 4) & 3) ^ (rA0 & 3);
  const bf16_t* Asrc0 = Ab + (size_t)(rowbase + rA0) * K + cbA * 8;
  const bf16_t* Asrc1 = Ab + (size_t)(rowbase + rA0 + 16) * K + cbA * 8;
  const bf16_t* Bsrc0 = Bb + (size_t)(c0 + rA0) * K + cbA * 8;
  const bf16_t* Bsrc1 = Bb + (size_t)(c0 + rA0 + 16) * K + cbA * 8;

  f32x4 acc[4][4];
#pragma unroll
  for (int m = 0; m < 4; m++)
#pragma unroll
    for (int n = 0; n < 4; n++) acc[m][n] = (f32x4){0.f, 0.f, 0.f, 0.f};

  gload_lds16(Asrc0, (char*)&lA[0][0] + wid * 2048);
  gload_lds16(Asrc1, (char*)&lA[0][0] + wid * 2048 + 1024);
  gload_lds16(Bsrc0, (char*)&lB[0][0] + wid * 2048);
  gload_lds16(Bsrc1, (char*)&lB[0][0] + wid * 2048 + 1024);
  __syncthreads();

  for (int k0 = 0; k0 < KS; k0 += 32) {
    int buf = (k0 >> 5) & 1;
    if (k0 + 32 < KS) {
      gload_lds16(Asrc0 + k0 + 32, (char*)&lA[buf ^ 1][0] + wid * 2048);
      gload_lds16(Asrc1 + k0 + 32, (char*)&lA[buf ^ 1][0] + wid * 2048 + 1024);
      gload_lds16(Bsrc0 + k0 + 32, (char*)&lB[buf ^ 1][0] + wid * 2048);
      gload_lds16(Bsrc1 + k0 + 32, (char*)&lB[buf ^ 1][0] + wid * 2048 + 1024);
    }
    const char* cA = (const char*)&lA[buf][0];
    const char* cB = (const char*)&lB[buf][0];
    bf16x8 af[4], bq[4];
#pragma unroll
    for (int m = 0; m < 4; m++) {
      int row = wr * 64 + m * 16 + l16;
      af[m] = *(const bf16x8*)(cA + row * 64 + ((g ^ (row & 3)) << 4));
    }
#pragma unroll
    for (int n = 0; n < 4; n++) {
      int row = wc * 64 + n * 16 + l16;
      bq[n] = *(const bf16x8*)(cB + row * 64 + ((g ^ (row & 3)) << 4));
    }
#pragma unroll
    for (int m = 0; m < 4; m++)
#pragma unroll
      for (int n = 0; n < 4; n++) acc[m][n] = mfma16(af[m], bq[n], acc[m][n]);
    __syncthreads();
  }

  int which = c0 / out_ncols;
  int cloc0 = c0 - which * out_ncols;
  size_t obase = (size_t)which * 8192 * out_ncols +
                 (size_t)split * 8192 * out_ncols * (NSPLIT > 1 ? 1 : 0);
  float osc = (EPI == 0 && which == 0) ? QSCALE : 1.0f;  // q pre-scale (base-2)
#pragma unroll
  for (int n = 0; n < 4; n++) {
    int col = cloc0 + wc * 64 + n * 16 + l16;
    float bv = (EPI >= 1 && bias && split == 0) ? bias[col] : 0.f;
#pragma unroll
    for (int m = 0; m < 4; m++)
#pragma unroll
      for (int j = 0; j < 4; j++) {
        int row = rowbase + wr * 64 + m * 16 + g * 4 + j;
        float v = acc[m][n][j] + bv;
        size_t idx = obase + (size_t)row * out_ncols + col;
        if (EPI == 1) outb[idx] = (__bf16)fmaxf(v, 0.f);
        else if (EPI == 0) outb[idx] = (__bf16)(v * osc);
        else outf[idx] = v;
      }
  }
}

// ---------------- residual + LayerNorm: sums nsplit f32 partials ----------------
__global__ __launch_bounds__(256) void k_resln(const float* __restrict__ gin,
                                               int nsplit,
                                               const float* __restrict__ residf,
                                               const bf16_t* __restrict__ residb,
                                               const float* __restrict__ gam,
                                               const float* __restrict__ bet,
                                               float* __restrict__ outf,
                                               bf16_t* __restrict__ outb) {
  const size_t GS = (size_t)8192 * 512;
  int row = blockIdx.x * 4 + (threadIdx.x >> 6);
  int lane = threadIdx.x & 63;
  const float* gp = gin + (size_t)row * 512;
  float4 a0 = ((const float4*)gp)[lane];
  float4 a1 = ((const float4*)gp)[lane + 64];
  for (int s = 1; s < nsplit; s++) {
    const float* gp2 = gp + s * GS;
    float4 r0 = ((const float4*)gp2)[lane];
    float4 r1 = ((const float4*)gp2)[lane + 64];
    a0.x += r0.x; a0.y += r0.y; a0.z += r0.z; a0.w += r0.w;
    a1.x += r1.x; a1.y += r1.y; a1.z += r1.z; a1.w += r1.w;
  }
  if (residf) {
    const float* rp = residf + (size_t)row * 512;
    float4 r0 = ((const float4*)rp)[lane];
    float4 r1 = ((const float4*)rp)[lane + 64];
    a0.x += r0.x; a0.y += r0.y; a0.z += r0.z; a0.w += r0.w;
    a1.x += r1.x; a1.y += r1.y; a1.z += r1.z; a1.w += r1.w;
  } else {
    const bf16_t* rp = residb + (size_t)row * 512;
    bf16x4 r0 = ((const bf16x4*)rp)[lane];
    bf16x4 r1 = ((const bf16x4*)rp)[lane + 64];
    a0.x += (float)r0[0]; a0.y += (float)r0[1]; a0.z += (float)r0[2]; a0.w += (float)r0[3];
    a1.x += (float)r1[0]; a1.y += (float)r1[1]; a1.z += (float)r1[2]; a1.w += (float)r1[3];
  }
  float s = a0.x + a0.y + a0.z + a0.w + a1.x + a1.y + a1.z + a1.w;
  for (int off = 1; off < 64; off <<= 1) s += __shfl_xor(s, off);
  float mu = s * (1.f / 512.f);
  float sq = (a0.x - mu) * (a0.x - mu) + (a0.y - mu) * (a0.y - mu) +
             (a0.z - mu) * (a0.z - mu) + (a0.w - mu) * (a0.w - mu) +
             (a1.x - mu) * (a1.x - mu) + (a1.y - mu) * (a1.y - mu) +
             (a1.z - mu) * (a1.z - mu) + (a1.w - mu) * (a1.w - mu);
  for (int off = 1; off < 64; off <<= 1) sq += __shfl_xor(sq, off);
  float rs = rsqrtf(sq * (1.f / 512.f) + EPSC);

  float4 g0 = ((const float4*)gam)[lane], g1v = ((const float4*)gam)[lane + 64];
  float4 b0 = ((const float4*)bet)[lane], b1v = ((const float4*)bet)[lane + 64];
  float4 o0, o1;
  o0.x = (a0.x - mu) * rs * g0.x + b0.x;  o0.y = (a0.y - mu) * rs * g0.y + b0.y;
  o0.z = (a0.z - mu) * rs * g0.z + b0.z;  o0.w = (a0.w - mu) * rs * g0.w + b0.w;
  o1.x = (a1.x - mu) * rs * g1v.x + b1v.x; o1.y = (a1.y - mu) * rs * g1v.y + b1v.y;
  o1.z = (a1.z - mu) * rs * g1v.z + b1v.z; o1.w = (a1.w - mu) * rs * g1v.w + b1v.w;
  if (outf) {
    float* op = outf + (size_t)row * 512;
    ((float4*)op)[lane] = o0;
    ((float4*)op)[lane + 64] = o1;
  }
  if (outb) {
    bf16_t* op = outb + (size_t)row * 512;
    bf16x4 q0 = { (__bf16)o0.x, (__bf16)o0.y, (__bf16)o0.z, (__bf16)o0.w };
    bf16x4 q1 = { (__bf16)o1.x, (__bf16)o1.y, (__bf16)o1.z, (__bf16)o1.w };
    ((bf16x4*)op)[lane] = q0;
    ((bf16x4*)op)[lane + 64] = q1;
  }
}

// ---------------- v transpose (blk<1024) + kmax (blk>=1024) ----------------
__global__ __launch_bounds__(256) void k_vtrans_knorm(const bf16_t* __restrict__ v,
                                                      bf16_t* __restrict__ vT,
                                                      const bf16_t* __restrict__ kk,
                                                      float* __restrict__ kmax) {
  __shared__ bf16_t t[64 * 66];
  __shared__ float red[4];
  int bid = blockIdx.x;
  int tid = threadIdx.x, wid = tid >> 6, lane = tid & 63;
  if (bid < 1024) {
    int nt = bid & 15, h = (bid >> 4) & 7, b = bid >> 7;
    for (int i = 0; i < 16; i++) {
      int n = wid * 16 + i;
      t[lane * 66 + n] = v[(size_t)(b * 1024 + nt * 64 + n) * 512 + h * 64 + lane];
    }
    __syncthreads();
    for (int i = 0; i < 16; i++) {
      int d = wid * 16 + i;
      vT[(size_t)((b * 8 + h) * 64 + d) * 1024 + nt * 64 + lane] = t[d * 66 + lane];
    }
  } else {
    int bh = bid - 1024;
    int b = bh >> 3, h = bh & 7;
    float mx = 0.f;
    for (int n = tid; n < 1024; n += 256) {
      const bf16_t* kp = kk + (size_t)(b * 1024 + n) * 512 + h * 64;
      float ss = 0.f;
#pragma unroll
      for (int vv = 0; vv < 8; vv++) {
        bf16x8 kv = *(const bf16x8*)(kp + vv * 8);
#pragma unroll
        for (int e = 0; e < 8; e++) { float f = (float)kv[e]; ss += f * f; }
      }
      mx = fmaxf(mx, ss);
    }
    for (int off = 1; off < 64; off <<= 1) mx = fmaxf(mx, __shfl_xor(mx, off));
    if (lane == 0) red[wid] = mx;
    __syncthreads();
    if (tid == 0) kmax[bh] = sqrtf(fmaxf(fmaxf(red[0], red[1]), fmaxf(red[2], red[3])));
  }
}

// ---------------- attention: ctx (normalized) + crl = C + log2(l) ----------------
// grid 512: bid = qt*64 + (h + 8b). Block: 512 threads (8 waves x 16 q = 128 q),
// full k = 16 tiles of 64, FULLY UNROLLED. Triple-buffered K/vT staging with
// raw s_barrier + counted vmcnt (6/4/-, never 0 in steady loop). -C folded
// into MFMA C-in. eadj read as bf16x4 from the permuted table.
__global__ __launch_bounds__(512) void k_attn_ctx(const bf16_t* __restrict__ q,
                                                  const bf16_t* __restrict__ kk,
                                                  const bf16_t* __restrict__ vT,
                                                  const bf16_t* __restrict__ eadjP,
                                                  const float* __restrict__ kmax,
                                                  bf16_t* __restrict__ ctx,
                                                  float* __restrict__ crl) {
  __shared__ bf16_t ldsK[3][4096];
  __shared__ bf16_t ldsV[3][4096];
  __shared__ bf16_t pt[8][16 * 68];
  int bid = blockIdx.x;
  int qt = bid >> 6, h = bid & 7, b = (bid >> 3) & 7;
  int tid = threadIdx.x, wid = tid >> 6, lane = tid & 63;
  int l16 = lane & 15, g = lane >> 4;
  int qg0 = qt * 128 + wid * 16;
  int kvbase = (b * 8 + h) * 64;

  int d0 = wid * 1024 + lane * 16;
  int row0 = d0 >> 7;
  int cb0 = ((d0 >> 4) & 7) ^ (row0 & 7);
  const bf16_t* ksrc = kk + (size_t)(b * 1024) * 512 + h * 64;
  const bf16_t* vsrc = vT + (size_t)kvbase * 1024;

  auto stage = [&](int buf, int kc0) {
    gload_lds16(ksrc + (size_t)(kc0 + row0) * 512 + cb0 * 8, &ldsK[buf][wid * 512]);
    gload_lds16(vsrc + (size_t)row0 * 1024 + kc0 + cb0 * 8, &ldsV[buf][wid * 512]);
  };

  const bf16_t* qp = q + (size_t)(b * 1024 + qg0 + l16) * 512 + h * 64 + 8 * g;
  bf16x8 aq0 = *(const bf16x8*)qp;
  bf16x8 aq1 = *(const bf16x8*)(qp + 32);

  // C = |q'| * kmax from fragments (lane l16 holds row l16's 16 elems per g)
  float kmaxv = kmax[b * 8 + h];
  float ssq = 0.f;
#pragma unroll
  for (int e = 0; e < 8; e++) {
    float f0 = (float)aq0[e], f1 = (float)aq1[e];
    ssq += f0 * f0 + f1 * f1;
  }
  ssq += __shfl_xor(ssq, 16);
  ssq += __shfl_xor(ssq, 32);
  float Cn = sqrtf(ssq) * kmaxv;
  f32x4 negC;
#pragma unroll
  for (int j = 0; j < 4; j++) negC[j] = -__shfl(Cn, g * 4 + j);

  f32x4 cacc[4];
#pragma unroll
  for (int d = 0; d < 4; d++) cacc[d] = (f32x4){0.f, 0.f, 0.f, 0.f};
  float ls[4] = {0.f, 0.f, 0.f, 0.f};
  bf16_t* myp = pt[wid];
  int rph = l16 & 7;
  // permuted eadj: row r, 64-group kc0, lane l16 -> bf16x4 at r*1024 + kc0 + l16*4
  const bf16_t* erowP = eadjP + (size_t)(qg0 + g * 4) * 1024 + l16 * 4;

  bf16x4 ea0[4], ea1[4];
  auto loadEA = [&](bf16x4 (&d)[4], int kc0) {
#pragma unroll
    for (int j = 0; j < 4; j++)
      d[j] = *(const bf16x4*)(erowP + (size_t)j * 1024 + kc0);
  };

  auto computeTile = [&](int buf, const bf16x4 (&eaC)[4]) {
    const char* curK = (const char*)ldsK[buf];
    const char* curV = (const char*)ldsV[buf];
#pragma unroll
    for (int cg = 0; cg < 4; cg++) {
      const char* krow = curK + ((cg * 16 + l16) << 7);
      bf16x8 k0 = *(const bf16x8*)(krow + ((g ^ rph) << 4));
      bf16x8 k1 = *(const bf16x8*)(krow + (((g + 4) ^ rph) << 4));
      __builtin_amdgcn_s_setprio(1);
      f32x4 s = mfma16(aq0, k0, negC);
      s = mfma16(aq1, k1, s);
      __builtin_amdgcn_s_setprio(0);
#pragma unroll
      for (int j = 0; j < 4; j++) {
        float p = (float)eaC[j][cg] * exp2f(s[j]);
        ls[j] += p;
        myp[(g * 4 + j) * 68 + cg * 16 + l16] = (__bf16)p;
      }
    }
#pragma unroll
    for (int half = 0; half < 2; half++) {
      bf16x8 pa = *(const bf16x8*)(myp + l16 * 68 + half * 32 + 8 * g);
      __builtin_amdgcn_s_setprio(1);
#pragma unroll
      for (int dg = 0; dg < 4; dg++) {
        const char* vrow = curV + ((dg * 16 + l16) << 7);
        bf16x8 vv = *(const bf16x8*)(vrow + (((g + half * 4) ^ rph) << 4));
        cacc[dg] = mfma16(pa, vv, cacc[dg]);
      }
      __builtin_amdgcn_s_setprio(0);
    }
  };

  // prologue: stage tiles 0,1; load ea(0). newest-6 outstanding = stage(1)+ea(0)
  stage(0, 0);
  stage(1, 64);
  loadEA(ea0, 0);
  __builtin_amdgcn_sched_barrier(0);
  asm volatile("s_waitcnt vmcnt(6) lgkmcnt(0)" ::: "memory");
  __builtin_amdgcn_sched_barrier(0);
  __builtin_amdgcn_s_barrier();
  __builtin_amdgcn_sched_barrier(0);

#pragma unroll
  for (int kt = 0; kt < 16; ++kt) {
    const int buf = kt % 3;
    if (kt + 2 < 16) stage((kt + 2) % 3, (kt + 2) * 64);
    if (kt + 1 < 16) {
      if ((kt & 1) == 0) loadEA(ea1, (kt + 1) * 64);
      else               loadEA(ea0, (kt + 1) * 64);
    }
    if ((kt & 1) == 0) computeTile(buf, ea0);
    else               computeTile(buf, ea1);
    if (kt < 15) {
      __builtin_amdgcn_sched_barrier(0);
      if (kt < 14)
        asm volatile("s_waitcnt vmcnt(6) lgkmcnt(0)" ::: "memory");
      else
        asm volatile("s_waitcnt vmcnt(4) lgkmcnt(0)" ::: "memory");
      __builtin_amdgcn_sched_barrier(0);
      __builtin_amdgcn_s_barrier();
      __builtin_amdgcn_sched_barrier(0);
    }
  }

#pragma unroll
  for (int j = 0; j < 4; j++)
    for (int off = 1; off < 16; off <<= 1) ls[j] += __shfl_xor(ls[j], off);
  float rc[4];
#pragma unroll
  for (int j = 0; j < 4; j++) rc[j] = (ls[j] > 0.f) ? (1.f / ls[j]) : 0.f;

#pragma unroll
  for (int dg = 0; dg < 4; dg++)
#pragma unroll
    for (int j = 0; j < 4; j++) {
      int row = qg0 + g * 4 + j;
      ctx[(size_t)(b * 1024 + row) * 512 + h * 64 + dg * 16 + l16] =
          (__bf16)(cacc[dg][j] * rc[j]);
    }
  if (l16 == 0) {
#pragma unroll
    for (int j = 0; j < 4; j++) {
      int li = (b * 8 + h) * 1024 + qg0 + g * 4 + j;
      crl[li] = (ls[j] > 0.f) ? (-negC[j] + __log2f(ls[j])) : 1.0e30f;
    }
  }
}

// ---------------- attention mean over heads -> mout (barrier-free) ----------------
// mean = eadj * (1/8) * sum_h exp2(s_h - crl_h); -crl folded into MFMA C-in.
__global__ __launch_bounds__(256, 4) void k_attn_mean(const bf16_t* __restrict__ q,
                                                      const bf16_t* __restrict__ kk,
                                                      const bf16_t* __restrict__ eadjP,
                                                      const float* __restrict__ crl,
                                                      float* __restrict__ mout) {
  __shared__ bf16_t lds[4][2][2048];   // [wave][buf][4KB]
  int bid = blockIdx.x;
  int kq = bid & 7, qt = (bid >> 3) & 15, b = bid >> 7;
  int tid = threadIdx.x, wid = tid >> 6, lane = tid & 63;
  int l16 = lane & 15, g = lane >> 4;
  int qg0 = qt * 64 + wid * 16;
  int kbase = kq * 128;
  int rl = lane >> 3;
  int cb = (lane & 7) ^ rl;
  const bf16_t* ksrc = kk + (size_t)(b * 1024 + kbase) * 512;

  auto stage = [&](int t) {
    int h = t >> 2, c = t & 3;
    char* dst = (char*)&lds[wid][t & 1][0];
    const bf16_t* sp = ksrc + (size_t)(c * 32 + rl) * 512 + h * 64 + cb * 8;
#pragma unroll
    for (int i = 0; i < 4; i++)
      gload_lds16(sp + (size_t)i * 8 * 512, dst + i * 1024);
  };

  f32x4 macc[8];
#pragma unroll
  for (int kg = 0; kg < 8; kg++) macc[kg] = (f32x4){0.f, 0.f, 0.f, 0.f};

  stage(0);

  for (int h = 0; h < 8; h++) {
    const bf16_t* qp = q + (size_t)(b * 1024 + qg0 + l16) * 512 + h * 64 + 8 * g;
    bf16x8 aq0 = *(const bf16x8*)qp;
    bf16x8 aq1 = *(const bf16x8*)(qp + 32);
    f32x4 CR = *(const f32x4*)(crl + (b * 8 + h) * 1024 + qg0 + g * 4);
    f32x4 negCR = (f32x4){-CR[0], -CR[1], -CR[2], -CR[3]};
#pragma unroll
    for (int c = 0; c < 4; c++) {
      int t = h * 4 + c;
      __builtin_amdgcn_sched_barrier(0);
      if (t < 31) {
        stage(t + 1);
        __builtin_amdgcn_sched_barrier(0);
        asm volatile("s_waitcnt vmcnt(4)" ::: "memory");
      } else {
        asm volatile("s_waitcnt vmcnt(0)" ::: "memory");
      }
      __builtin_amdgcn_sched_barrier(0);
      const char* cK = (const char*)&lds[wid][t & 1][0];
#pragma unroll
      for (int cg = 0; cg < 2; cg++) {
        const char* krow = cK + ((cg * 16 + l16) << 7);
        bf16x8 k0 = *(const bf16x8*)(krow + ((g ^ (l16 & 7)) << 4));
        bf16x8 k1 = *(const bf16x8*)(krow + (((g + 4) ^ (l16 & 7)) << 4));
        __builtin_amdgcn_s_setprio(1);
        f32x4 s = mfma16(aq0, k0, negCR);
        s = mfma16(aq1, k1, s);
        __builtin_amdgcn_s_setprio(0);
        int kg = c * 2 + cg;
#pragma unroll
        for (int j = 0; j < 4; j++)
          macc[kg][j] += exp2f(s[j]);
      }
    }
  }

  // epilogue: multiply by eadj/8 (permuted table read) and store
#pragma unroll
  for (int kg = 0; kg < 8; kg++)
#pragma unroll
    for (int j = 0; j < 4; j++) {
      size_t row = qg0 + g * 4 + j;
      size_t off = row * 1024 + kbase + kg * 16 + l16;
      size_t poff = row * 1024 + 64 * (kq * 2 + (kg >> 2)) + l16 * 4 + (kg & 3);
      mout[(size_t)b * 1048576 + off] = macc[kg][j] * (float)eadjP[poff] * 0.125f;
    }
}

extern "C" void kernel_launch(void* const* d_in, const int* in_sizes, int n_in,
                              void* d_out, int out_size, void* d_ws, size_t ws_size,
                              hipStream_t stream) {
  (void)in_sizes; (void)n_in; (void)out_size; (void)ws_size;
  const float* x   = (const float*)d_in[0];
  const float* adj = (const float*)d_in[1];
  const int*   msk = (const int*)d_in[2];
  const float* Wq  = (const float*)d_in[3];
  const float* Wk  = (const float*)d_in[4];
  const float* Wv  = (const float*)d_in[5];
  const float* Wo  = (const float*)d_in[6];
  const float* W1  = (const float*)d_in[7];
  const float* b1  = (const float*)d_in[8];
  const float* W2  = (const float*)d_in[9];
  const float* b2  = (const float*)d_in[10];
  const float* g1  = (const float*)d_in[11];
  const float* be1 = (const float*)d_in[12];
  const float* g2  = (const float*)d_in[13];
  const float* be2 = (const float*)d_in[14];

  float* out  = (float*)d_out;
  float* mout = out + (size_t)8 * 1024 * 512;

  char* ws = (char*)d_ws;
  const size_t MB = 1024 * 1024;
  bf16_t* wqb = (bf16_t*)(ws);
  bf16_t* wkb = (bf16_t*)(ws + 512 * 1024);
  bf16_t* wvb = (bf16_t*)(ws + 1 * MB);
  bf16_t* wob = (bf16_t*)(ws + 3 * MB / 2);
  bf16_t* w1b = (bf16_t*)(ws + 2 * MB);
  bf16_t* w2b = (bf16_t*)(ws + 4 * MB);
  float*  crl  = (float*)(ws + 6 * MB + 256 * 1024); // 256 KB (C + log2 l)
  float*  kmax = (float*)(ws + 6 * MB + 768 * 1024); // 256 B
  bf16_t* xb   = (bf16_t*)(ws + 8 * MB);   // 8-16: x bf16; then ctx; then zb
  bf16_t* ctx  = xb;
  bf16_t* zb   = xb;
  bf16_t* qb   = (bf16_t*)(ws + 16 * MB);  // 16-24 (dead after attn_mean)
  bf16_t* kb   = (bf16_t*)(ws + 24 * MB);  // 24-32 (dead after attn_mean)
  bf16_t* vb   = (bf16_t*)(ws + 32 * MB);  // 32-40 (dead after vtrans)
  bf16_t* vT   = (bf16_t*)(ws + 40 * MB);  // 40-48 (dead after attn_ctx)
  float*  gout1 = (float*)(ws + 16 * MB);  // 16-48: 2x16MB f32 (wo split-K partials)
  bf16_t* hb    = (bf16_t*)(ws + 16 * MB); // 16-48 bf16 (ffn1 -> ffn2)
  float*  gout2 = (float*)(ws + 44 * MB);  // 44-76: 2x16MB f32 (ffn2 split-K partials)
  bf16_t* eadjP = (bf16_t*)(ws + 72 * MB); // 72-74 permuted exp(adj)*mask table
  // eadjP (72-74) overlaps gout2 split1 (60-76): eadjP is dead after attn_mean,
  // which completes before the ffn2 gemm writes gout2. Safe.

  // converts + eadj prep (one launch)
  k_cvtall<<<7424, 256, 0, stream>>>(x, Wq, Wk, Wv, Wo, W1, W2, adj, msk,
                                     xb, wqb, wkb, wvb, wob, w1b, w2b, eadjP);

  // QKV: one GEMM, N=1536 (wq|wk|wv contiguous); q pre-scaled by 0.125*log2e
  k_gemm<0, 1><<<64 * 12, 256, 0, stream>>>(xb, wqb, 512, 12, nullptr, qb, nullptr, 512);
  // v transpose + kmax in one launch
  k_vtrans_knorm<<<1088, 256, 0, stream>>>(vb, vT, kb, kmax);

  // attention: ctx (counted-vmcnt pipeline) + crl, then mean
  k_attn_ctx<<<512, 512, 0, stream>>>(qb, kb, vT, eadjP, kmax, ctx, crl);
  k_attn_mean<<<1024, 256, 0, stream>>>(qb, kb, eadjP, crl, mout);

  // Wo proj (split-K x2) -> gout1[2]; residual(x f32) + LN1 -> zb (bf16)
  k_gemm<2, 2><<<2 * 64 * 4, 256, 0, stream>>>(ctx, wob, 512, 4, nullptr, nullptr, gout1, 512);
  k_resln<<<2048, 256, 0, stream>>>(gout1, 2, x, nullptr, g1, be1, nullptr, zb);
  // FFN1: relu(zb @ W1^T + b1) -> hb
  k_gemm<1, 1><<<64 * 16, 256, 0, stream>>>(zb, w1b, 512, 16, b1, hb, nullptr, 2048);
  // FFN2 (split-K x2) -> gout2[2]; residual(zb bf16) + LN2 -> out
  k_gemm<2, 2><<<2 * 64 * 4, 256, 0, stream>>>(hb, w2b, 2048, 4, b2, nullptr, gout2, 512);
  k_resln<<<2048, 256, 0, stream>>>(gout2, 2, nullptr, zb, g2, be2, out, nullptr);
}

// Round 12
// 228.585 us; speedup vs baseline: 1.0524x; 1.0524x over previous
//
#include <hip/hip_runtime.h>
#include <math.h>
#include <stdint.h>

// GraphTransformerLayer on MI355X (gfx950).
// B=8, N=1024, D=512, H=8, Dh=64, F=2048.
// Round 12: attn_ctx = round-10 double-buffer structure (50KB LDS, 3 blk/CU,
//           rolled loop) + COUNTED vmcnt(4)/s_barrier instead of __syncthreads
//           (never drains to 0 in steady loop). Keeps r11's eadjP permuted
//           table, -C folded into MFMA C-in, merged cvtall launch.

using bf16_t = __bf16;
typedef __attribute__((__ext_vector_type__(8))) __bf16 bf16x8;
typedef __attribute__((__ext_vector_type__(4))) __bf16 bf16x4;
typedef __attribute__((__ext_vector_type__(4))) float  f32x4;

#define DEVI __device__ __forceinline__

DEVI f32x4 mfma16(bf16x8 a, bf16x8 b, f32x4 c) {
  return __builtin_amdgcn_mfma_f32_16x16x32_bf16(a, b, c, 0, 0, 0);
}

// async global->LDS, 16B per lane. dest = wave-uniform base (+ lane*16 by HW).
DEVI void gload_lds16(const void* g, void* l) {
  __builtin_amdgcn_global_load_lds(
      (const __attribute__((address_space(1))) uint32_t*)g,
      (__attribute__((address_space(3))) uint32_t*)l, 16, 0, 0);
}

#define EPSC  (1e-5f)
#define QSCALE 0.18033688f   // 0.125 * log2(e): scores come out of MFMA in base-2

// ---------------- fused converts: x (4096) + weights (3072) + eadj prep (256) ----------------
// eadj stored PERMUTED within each 64-col group: pos = (c&15)*4 + ((c>>4)&3)
// so ctx lane l16 reads cols {l16, 16+l16, 32+l16, 48+l16} as one bf16x4.
__global__ __launch_bounds__(256) void k_cvtall(const float* __restrict__ x,
                                                const float* __restrict__ wq,
                                                const float* __restrict__ wk,
                                                const float* __restrict__ wv,
                                                const float* __restrict__ wo,
                                                const float* __restrict__ w1,
                                                const float* __restrict__ w2,
                                                const float* __restrict__ adj,
                                                const int* __restrict__ msk,
                                                bf16_t* __restrict__ ox,
                                                bf16_t* __restrict__ owq,
                                                bf16_t* __restrict__ owk,
                                                bf16_t* __restrict__ owv,
                                                bf16_t* __restrict__ owo,
                                                bf16_t* __restrict__ ow1,
                                                bf16_t* __restrict__ ow2,
                                                bf16_t* __restrict__ eadjP) {
  int blk = blockIdx.x;
  if (blk >= 7168) {  // eadj prep: 256 blocks x 4 rows
    int row  = (blk - 7168) * 4 + (threadIdx.x >> 6);
    int lane = threadIdx.x & 63;
    for (int i = 0; i < 16; i++) {
      int c = lane + 64 * i;
      size_t idx = (size_t)row * 1024 + c;
      float a = adj[idx];
      bool valid = (msk[idx] != 0);
      int pos = (c & ~63) + ((c & 15) << 2) + ((c >> 4) & 3);
      eadjP[(size_t)row * 1024 + pos] = valid ? (__bf16)__expf(a) : (__bf16)0.f;
    }
    return;
  }
  const float* src; bf16_t* dst; int base;
  if (blk < 4096)      { src = x;  dst = ox;  base = blk; }
  else {
    blk -= 4096;
    if      (blk < 256)  { src = wq; dst = owq; base = blk; }
    else if (blk < 512)  { src = wk; dst = owk; base = blk - 256; }
    else if (blk < 768)  { src = wv; dst = owv; base = blk - 512; }
    else if (blk < 1024) { src = wo; dst = owo; base = blk - 768; }
    else if (blk < 2048) { src = w1; dst = ow1; base = blk - 1024; }
    else                 { src = w2; dst = ow2; base = blk - 2048; }
  }
  int i = base * 256 + threadIdx.x;
  float4 v = ((const float4*)src)[i];
  bf16x4 o = { (__bf16)v.x, (__bf16)v.y, (__bf16)v.z, (__bf16)v.w };
  ((bf16x4*)dst)[i] = o;
}

// ---------------- tiled GEMM: C[8192 x N] = A[8192 x K] @ B[N x K]^T ----------------
// 128x128 tile, 4 waves (2x2), each wave 64x64 (4x4 fragments). BK=32.
// NSPLIT>1: K split into NSPLIT slices; slice s writes outf + s*8192*out_ncols.
template<int EPI, int NSPLIT>
__global__ __launch_bounds__(256) void k_gemm(const bf16_t* __restrict__ A,
                                              const bf16_t* __restrict__ B,
                                              int K, int nbx,
                                              const float* __restrict__ bias,
                                              bf16_t* __restrict__ outb,
                                              float* __restrict__ outf,
                                              int out_ncols) {
  __shared__ bf16_t lA[2][4096];
  __shared__ bf16_t lB[2][4096];
  int bid = blockIdx.x;
  int bps = 64 * nbx;                 // blocks per split (M/128 = 64)
  int split = bid / bps, r = bid - split * bps;
  int nb = r % nbx, mb = r / nbx;
  int KS = K / NSPLIT;
  const bf16_t* Ab = A + (size_t)split * KS;
  const bf16_t* Bb = B + (size_t)split * KS;
  int tid = threadIdx.x, wid = tid >> 6, lane = tid & 63;
  int l16 = lane & 15, g = lane >> 4;
  int wr = wid >> 1, wc = wid & 1;
  int rowbase = mb * 128, c0 = nb * 128;

  int dA0 = wid * 2048 + lane * 16;
  int rA0 = dA0 >> 6;
  int cbA = ((dA0 >> 4) & 3) ^ (rA0 & 3);
  const bf16_t* Asrc0 = Ab + (size_t)(rowbase + rA0) * K + cbA * 8;
  const bf16_t* Asrc1 = Ab + (size_t)(rowbase + rA0 + 16) * K + cbA * 8;
  const bf16_t* Bsrc0 = Bb + (size_t)(c0 + rA0) * K + cbA * 8;
  const bf16_t* Bsrc1 = Bb + (size_t)(c0 + rA0 + 16) * K + cbA * 8;

  f32x4 acc[4][4];
#pragma unroll
  for (int m = 0; m < 4; m++)
#pragma unroll
    for (int n = 0; n < 4; n++) acc[m][n] = (f32x4){0.f, 0.f, 0.f, 0.f};

  gload_lds16(Asrc0, (char*)&lA[0][0] + wid * 2048);
  gload_lds16(Asrc1, (char*)&lA[0][0] + wid * 2048 + 1024);
  gload_lds16(Bsrc0, (char*)&lB[0][0] + wid * 2048);
  gload_lds16(Bsrc1, (char*)&lB[0][0] + wid * 2048 + 1024);
  __syncthreads();

  for (int k0 = 0; k0 < KS; k0 += 32) {
    int buf = (k0 >> 5) & 1;
    if (k0 + 32 < KS) {
      gload_lds16(Asrc0 + k0 + 32, (char*)&lA[buf ^ 1][0] + wid * 2048);
      gload_lds16(Asrc1 + k0 + 32, (char*)&lA[buf ^ 1][0] + wid * 2048 + 1024);
      gload_lds16(Bsrc0 + k0 + 32, (char*)&lB[buf ^ 1][0] + wid * 2048);
      gload_lds16(Bsrc1 + k0 + 32, (char*)&lB[buf ^ 1][0] + wid * 2048 + 1024);
    }
    const char* cA = (const char*)&lA[buf][0];
    const char* cB = (const char*)&lB[buf][0];
    bf16x8 af[4], bq[4];
#pragma unroll
    for (int m = 0; m < 4; m++) {
      int row = wr * 64 + m * 16 + l16;
      af[m] = *(const bf16x8*)(cA + row * 64 + ((g ^ (row & 3)) << 4));
    }
#pragma unroll
    for (int n = 0; n < 4; n++) {
      int row = wc * 64 + n * 16 + l16;
      bq[n] = *(const bf16x8*)(cB + row * 64 + ((g ^ (row & 3)) << 4));
    }
#pragma unroll
    for (int m = 0; m < 4; m++)
#pragma unroll
      for (int n = 0; n < 4; n++) acc[m][n] = mfma16(af[m], bq[n], acc[m][n]);
    __syncthreads();
  }

  int which = c0 / out_ncols;
  int cloc0 = c0 - which * out_ncols;
  size_t obase = (size_t)which * 8192 * out_ncols +
                 (size_t)split * 8192 * out_ncols * (NSPLIT > 1 ? 1 : 0);
  float osc = (EPI == 0 && which == 0) ? QSCALE : 1.0f;  // q pre-scale (base-2)
#pragma unroll
  for (int n = 0; n < 4; n++) {
    int col = cloc0 + wc * 64 + n * 16 + l16;
    float bv = (EPI >= 1 && bias && split == 0) ? bias[col] : 0.f;
#pragma unroll
    for (int m = 0; m < 4; m++)
#pragma unroll
      for (int j = 0; j < 4; j++) {
        int row = rowbase + wr * 64 + m * 16 + g * 4 + j;
        float v = acc[m][n][j] + bv;
        size_t idx = obase + (size_t)row * out_ncols + col;
        if (EPI == 1) outb[idx] = (__bf16)fmaxf(v, 0.f);
        else if (EPI == 0) outb[idx] = (__bf16)(v * osc);
        else outf[idx] = v;
      }
  }
}

// ---------------- residual + LayerNorm: sums nsplit f32 partials ----------------
__global__ __launch_bounds__(256) void k_resln(const float* __restrict__ gin,
                                               int nsplit,
                                               const float* __restrict__ residf,
                                               const bf16_t* __restrict__ residb,
                                               const float* __restrict__ gam,
                                               const float* __restrict__ bet,
                                               float* __restrict__ outf,
                                               bf16_t* __restrict__ outb) {
  const size_t GS = (size_t)8192 * 512;
  int row = blockIdx.x * 4 + (threadIdx.x >> 6);
  int lane = threadIdx.x & 63;
  const float* gp = gin + (size_t)row * 512;
  float4 a0 = ((const float4*)gp)[lane];
  float4 a1 = ((const float4*)gp)[lane + 64];
  for (int s = 1; s < nsplit; s++) {
    const float* gp2 = gp + s * GS;
    float4 r0 = ((const float4*)gp2)[lane];
    float4 r1 = ((const float4*)gp2)[lane + 64];
    a0.x += r0.x; a0.y += r0.y; a0.z += r0.z; a0.w += r0.w;
    a1.x += r1.x; a1.y += r1.y; a1.z += r1.z; a1.w += r1.w;
  }
  if (residf) {
    const float* rp = residf + (size_t)row * 512;
    float4 r0 = ((const float4*)rp)[lane];
    float4 r1 = ((const float4*)rp)[lane + 64];
    a0.x += r0.x; a0.y += r0.y; a0.z += r0.z; a0.w += r0.w;
    a1.x += r1.x; a1.y += r1.y; a1.z += r1.z; a1.w += r1.w;
  } else {
    const bf16_t* rp = residb + (size_t)row * 512;
    bf16x4 r0 = ((const bf16x4*)rp)[lane];
    bf16x4 r1 = ((const bf16x4*)rp)[lane + 64];
    a0.x += (float)r0[0]; a0.y += (float)r0[1]; a0.z += (float)r0[2]; a0.w += (float)r0[3];
    a1.x += (float)r1[0]; a1.y += (float)r1[1]; a1.z += (float)r1[2]; a1.w += (float)r1[3];
  }
  float s = a0.x + a0.y + a0.z + a0.w + a1.x + a1.y + a1.z + a1.w;
  for (int off = 1; off < 64; off <<= 1) s += __shfl_xor(s, off);
  float mu = s * (1.f / 512.f);
  float sq = (a0.x - mu) * (a0.x - mu) + (a0.y - mu) * (a0.y - mu) +
             (a0.z - mu) * (a0.z - mu) + (a0.w - mu) * (a0.w - mu) +
             (a1.x - mu) * (a1.x - mu) + (a1.y - mu) * (a1.y - mu) +
             (a1.z - mu) * (a1.z - mu) + (a1.w - mu) * (a1.w - mu);
  for (int off = 1; off < 64; off <<= 1) sq += __shfl_xor(sq, off);
  float rs = rsqrtf(sq * (1.f / 512.f) + EPSC);

  float4 g0 = ((const float4*)gam)[lane], g1v = ((const float4*)gam)[lane + 64];
  float4 b0 = ((const float4*)bet)[lane], b1v = ((const float4*)bet)[lane + 64];
  float4 o0, o1;
  o0.x = (a0.x - mu) * rs * g0.x + b0.x;  o0.y = (a0.y - mu) * rs * g0.y + b0.y;
  o0.z = (a0.z - mu) * rs * g0.z + b0.z;  o0.w = (a0.w - mu) * rs * g0.w + b0.w;
  o1.x = (a1.x - mu) * rs * g1v.x + b1v.x; o1.y = (a1.y - mu) * rs * g1v.y + b1v.y;
  o1.z = (a1.z - mu) * rs * g1v.z + b1v.z; o1.w = (a1.w - mu) * rs * g1v.w + b1v.w;
  if (outf) {
    float* op = outf + (size_t)row * 512;
    ((float4*)op)[lane] = o0;
    ((float4*)op)[lane + 64] = o1;
  }
  if (outb) {
    bf16_t* op = outb + (size_t)row * 512;
    bf16x4 q0 = { (__bf16)o0.x, (__bf16)o0.y, (__bf16)o0.z, (__bf16)o0.w };
    bf16x4 q1 = { (__bf16)o1.x, (__bf16)o1.y, (__bf16)o1.z, (__bf16)o1.w };
    ((bf16x4*)op)[lane] = q0;
    ((bf16x4*)op)[lane + 64] = q1;
  }
}

// ---------------- v transpose (blk<1024) + kmax (blk>=1024) ----------------
__global__ __launch_bounds__(256) void k_vtrans_knorm(const bf16_t* __restrict__ v,
                                                      bf16_t* __restrict__ vT,
                                                      const bf16_t* __restrict__ kk,
                                                      float* __restrict__ kmax) {
  __shared__ bf16_t t[64 * 66];
  __shared__ float red[4];
  int bid = blockIdx.x;
  int tid = threadIdx.x, wid = tid >> 6, lane = tid & 63;
  if (bid < 1024) {
    int nt = bid & 15, h = (bid >> 4) & 7, b = bid >> 7;
    for (int i = 0; i < 16; i++) {
      int n = wid * 16 + i;
      t[lane * 66 + n] = v[(size_t)(b * 1024 + nt * 64 + n) * 512 + h * 64 + lane];
    }
    __syncthreads();
    for (int i = 0; i < 16; i++) {
      int d = wid * 16 + i;
      vT[(size_t)((b * 8 + h) * 64 + d) * 1024 + nt * 64 + lane] = t[d * 66 + lane];
    }
  } else {
    int bh = bid - 1024;
    int b = bh >> 3, h = bh & 7;
    float mx = 0.f;
    for (int n = tid; n < 1024; n += 256) {
      const bf16_t* kp = kk + (size_t)(b * 1024 + n) * 512 + h * 64;
      float ss = 0.f;
#pragma unroll
      for (int vv = 0; vv < 8; vv++) {
        bf16x8 kv = *(const bf16x8*)(kp + vv * 8);
#pragma unroll
        for (int e = 0; e < 8; e++) { float f = (float)kv[e]; ss += f * f; }
      }
      mx = fmaxf(mx, ss);
    }
    for (int off = 1; off < 64; off <<= 1) mx = fmaxf(mx, __shfl_xor(mx, off));
    if (lane == 0) red[wid] = mx;
    __syncthreads();
    if (tid == 0) kmax[bh] = sqrtf(fmaxf(fmaxf(red[0], red[1]), fmaxf(red[2], red[3])));
  }
}

// ---------------- attention: ctx (normalized) + crl = C + log2(l) ----------------
// grid 512: bid = qt*64 + (h + 8b). Block: 512 threads (8 waves x 16 q = 128 q),
// full k = 16 tiles of 64, double-buffered K/vT staging via global_load_lds.
// COUNTED barrier per tile: s_waitcnt vmcnt(4) lgkmcnt(0) + raw s_barrier
// (stage(t+1)'s 2 loads are oldest of 6 outstanding; ea(t+1)'s 4 stay in
// flight, drained by compiler before use next tile). -C folded into MFMA C-in.
__global__ __launch_bounds__(512) void k_attn_ctx(const bf16_t* __restrict__ q,
                                                  const bf16_t* __restrict__ kk,
                                                  const bf16_t* __restrict__ vT,
                                                  const bf16_t* __restrict__ eadjP,
                                                  const float* __restrict__ kmax,
                                                  bf16_t* __restrict__ ctx,
                                                  float* __restrict__ crl) {
  __shared__ bf16_t ldsK[2][4096];
  __shared__ bf16_t ldsV[2][4096];
  __shared__ bf16_t pt[8][16 * 68];
  int bid = blockIdx.x;
  int qt = bid >> 6, h = bid & 7, b = (bid >> 3) & 7;
  int tid = threadIdx.x, wid = tid >> 6, lane = tid & 63;
  int l16 = lane & 15, g = lane >> 4;
  int qg0 = qt * 128 + wid * 16;
  int kvbase = (b * 8 + h) * 64;

  int d0 = wid * 1024 + lane * 16;
  int row0 = d0 >> 7;
  int cb0 = ((d0 >> 4) & 7) ^ (row0 & 7);
  const bf16_t* ksrc = kk + (size_t)(b * 1024) * 512 + h * 64;
  const bf16_t* vsrc = vT + (size_t)kvbase * 1024;

  auto stage = [&](int buf, int kc0) {
    gload_lds16(ksrc + (size_t)(kc0 + row0) * 512 + cb0 * 8, &ldsK[buf][wid * 512]);
    gload_lds16(vsrc + (size_t)row0 * 1024 + kc0 + cb0 * 8, &ldsV[buf][wid * 512]);
  };

  const bf16_t* qp = q + (size_t)(b * 1024 + qg0 + l16) * 512 + h * 64 + 8 * g;
  bf16x8 aq0 = *(const bf16x8*)qp;
  bf16x8 aq1 = *(const bf16x8*)(qp + 32);

  // C = |q'| * kmax from fragments (lane l16 holds row l16's 16 elems per g)
  float kmaxv = kmax[b * 8 + h];
  float ssq = 0.f;
#pragma unroll
  for (int e = 0; e < 8; e++) {
    float f0 = (float)aq0[e], f1 = (float)aq1[e];
    ssq += f0 * f0 + f1 * f1;
  }
  ssq += __shfl_xor(ssq, 16);
  ssq += __shfl_xor(ssq, 32);
  float Cn = sqrtf(ssq) * kmaxv;
  f32x4 negC;
#pragma unroll
  for (int j = 0; j < 4; j++) negC[j] = -__shfl(Cn, g * 4 + j);

  f32x4 cacc[4];
#pragma unroll
  for (int d = 0; d < 4; d++) cacc[d] = (f32x4){0.f, 0.f, 0.f, 0.f};
  float ls[4] = {0.f, 0.f, 0.f, 0.f};
  bf16_t* myp = pt[wid];
  int rph = l16 & 7;
  // permuted eadj: row r, 64-group kc0, lane l16 -> bf16x4 at r*1024 + kc0 + l16*4
  const bf16_t* erowP = eadjP + (size_t)(qg0 + g * 4) * 1024 + l16 * 4;

  bf16x4 ea0[4], ea1[4];
  auto loadEA = [&](bf16x4 (&d)[4], int kc0) {
#pragma unroll
    for (int j = 0; j < 4; j++)
      d[j] = *(const bf16x4*)(erowP + (size_t)j * 1024 + kc0);
  };

  // counted barrier: stage(t+1)'s 2 loads (oldest) must land; ea loads stay.
  auto cbar = [&]() {
    __builtin_amdgcn_sched_barrier(0);
    asm volatile("s_waitcnt vmcnt(4) lgkmcnt(0)" ::: "memory");
    __builtin_amdgcn_sched_barrier(0);
    __builtin_amdgcn_s_barrier();
    __builtin_amdgcn_sched_barrier(0);
  };

  auto tile = [&](int kt, int buf, bf16x4 (&eaC)[4], bf16x4 (&eaN)[4]) {
    int kc0 = kt * 64;
    int ktn = (kt + 1 < 16) ? kt + 1 : 15;   // clamped tail keeps counts uniform
    stage(buf ^ 1, ktn * 64);                // 2 loads (oldest outstanding)
    loadEA(eaN, ktn * 64);                   // 4 loads

    const char* curK = (const char*)ldsK[buf];
    const char* curV = (const char*)ldsV[buf];

#pragma unroll
    for (int cg = 0; cg < 4; cg++) {
      const char* krow = curK + ((cg * 16 + l16) << 7);
      bf16x8 k0 = *(const bf16x8*)(krow + ((g ^ rph) << 4));
      bf16x8 k1 = *(const bf16x8*)(krow + (((g + 4) ^ rph) << 4));
      __builtin_amdgcn_s_setprio(1);
      f32x4 s = mfma16(aq0, k0, negC);
      s = mfma16(aq1, k1, s);
      __builtin_amdgcn_s_setprio(0);
#pragma unroll
      for (int j = 0; j < 4; j++) {
        float p = (float)eaC[j][cg] * exp2f(s[j]);
        ls[j] += p;
        myp[(g * 4 + j) * 68 + cg * 16 + l16] = (__bf16)p;
      }
    }
#pragma unroll
    for (int half = 0; half < 2; half++) {
      bf16x8 pa = *(const bf16x8*)(myp + l16 * 68 + half * 32 + 8 * g);
      __builtin_amdgcn_s_setprio(1);
#pragma unroll
      for (int dg = 0; dg < 4; dg++) {
        const char* vrow = curV + ((dg * 16 + l16) << 7);
        bf16x8 vv = *(const bf16x8*)(vrow + (((g + half * 4) ^ rph) << 4));
        cacc[dg] = mfma16(pa, vv, cacc[dg]);
      }
      __builtin_amdgcn_s_setprio(0);
    }
    cbar();
  };

  // prologue: stage tile 0 + ea(0); wait for stage(0) only (ea stays in flight)
  stage(0, 0);
  loadEA(ea0, 0);
  cbar();

  for (int k2 = 0; k2 < 8; k2++) {
    tile(2 * k2,     0, ea0, ea1);
    tile(2 * k2 + 1, 1, ea1, ea0);
  }

#pragma unroll
  for (int j = 0; j < 4; j++)
    for (int off = 1; off < 16; off <<= 1) ls[j] += __shfl_xor(ls[j], off);
  float rc[4];
#pragma unroll
  for (int j = 0; j < 4; j++) rc[j] = (ls[j] > 0.f) ? (1.f / ls[j]) : 0.f;

#pragma unroll
  for (int dg = 0; dg < 4; dg++)
#pragma unroll
    for (int j = 0; j < 4; j++) {
      int row = qg0 + g * 4 + j;
      ctx[(size_t)(b * 1024 + row) * 512 + h * 64 + dg * 16 + l16] =
          (__bf16)(cacc[dg][j] * rc[j]);
    }
  if (l16 == 0) {
#pragma unroll
    for (int j = 0; j < 4; j++) {
      int li = (b * 8 + h) * 1024 + qg0 + g * 4 + j;
      crl[li] = (ls[j] > 0.f) ? (-negC[j] + __log2f(ls[j])) : 1.0e30f;
    }
  }
}

// ---------------- attention mean over heads -> mout (barrier-free) ----------------
// mean = eadj * (1/8) * sum_h exp2(s_h - crl_h); -crl folded into MFMA C-in.
__global__ __launch_bounds__(256, 4) void k_attn_mean(const bf16_t* __restrict__ q,
                                                      const bf16_t* __restrict__ kk,
                                                      const bf16_t* __restrict__ eadjP,
                                                      const float* __restrict__ crl,
                                                      float* __restrict__ mout) {
  __shared__ bf16_t lds[4][2][2048];   // [wave][buf][4KB]
  int bid = blockIdx.x;
  int kq = bid & 7, qt = (bid >> 3) & 15, b = bid >> 7;
  int tid = threadIdx.x, wid = tid >> 6, lane = tid & 63;
  int l16 = lane & 15, g = lane >> 4;
  int qg0 = qt * 64 + wid * 16;
  int kbase = kq * 128;
  int rl = lane >> 3;
  int cb = (lane & 7) ^ rl;
  const bf16_t* ksrc = kk + (size_t)(b * 1024 + kbase) * 512;

  auto stage = [&](int t) {
    int h = t >> 2, c = t & 3;
    char* dst = (char*)&lds[wid][t & 1][0];
    const bf16_t* sp = ksrc + (size_t)(c * 32 + rl) * 512 + h * 64 + cb * 8;
#pragma unroll
    for (int i = 0; i < 4; i++)
      gload_lds16(sp + (size_t)i * 8 * 512, dst + i * 1024);
  };

  f32x4 macc[8];
#pragma unroll
  for (int kg = 0; kg < 8; kg++) macc[kg] = (f32x4){0.f, 0.f, 0.f, 0.f};

  stage(0);

  for (int h = 0; h < 8; h++) {
    const bf16_t* qp = q + (size_t)(b * 1024 + qg0 + l16) * 512 + h * 64 + 8 * g;
    bf16x8 aq0 = *(const bf16x8*)qp;
    bf16x8 aq1 = *(const bf16x8*)(qp + 32);
    f32x4 CR = *(const f32x4*)(crl + (b * 8 + h) * 1024 + qg0 + g * 4);
    f32x4 negCR = (f32x4){-CR[0], -CR[1], -CR[2], -CR[3]};
#pragma unroll
    for (int c = 0; c < 4; c++) {
      int t = h * 4 + c;
      __builtin_amdgcn_sched_barrier(0);
      if (t < 31) {
        stage(t + 1);
        __builtin_amdgcn_sched_barrier(0);
        asm volatile("s_waitcnt vmcnt(4)" ::: "memory");
      } else {
        asm volatile("s_waitcnt vmcnt(0)" ::: "memory");
      }
      __builtin_amdgcn_sched_barrier(0);
      const char* cK = (const char*)&lds[wid][t & 1][0];
#pragma unroll
      for (int cg = 0; cg < 2; cg++) {
        const char* krow = cK + ((cg * 16 + l16) << 7);
        bf16x8 k0 = *(const bf16x8*)(krow + ((g ^ (l16 & 7)) << 4));
        bf16x8 k1 = *(const bf16x8*)(krow + (((g + 4) ^ (l16 & 7)) << 4));
        __builtin_amdgcn_s_setprio(1);
        f32x4 s = mfma16(aq0, k0, negCR);
        s = mfma16(aq1, k1, s);
        __builtin_amdgcn_s_setprio(0);
        int kg = c * 2 + cg;
#pragma unroll
        for (int j = 0; j < 4; j++)
          macc[kg][j] += exp2f(s[j]);
      }
    }
  }

  // epilogue: multiply by eadj/8 (permuted table read) and store
#pragma unroll
  for (int kg = 0; kg < 8; kg++)
#pragma unroll
    for (int j = 0; j < 4; j++) {
      size_t row = qg0 + g * 4 + j;
      size_t off = row * 1024 + kbase + kg * 16 + l16;
      size_t poff = row * 1024 + 64 * (kq * 2 + (kg >> 2)) + l16 * 4 + (kg & 3);
      mout[(size_t)b * 1048576 + off] = macc[kg][j] * (float)eadjP[poff] * 0.125f;
    }
}

extern "C" void kernel_launch(void* const* d_in, const int* in_sizes, int n_in,
                              void* d_out, int out_size, void* d_ws, size_t ws_size,
                              hipStream_t stream) {
  (void)in_sizes; (void)n_in; (void)out_size; (void)ws_size;
  const float* x   = (const float*)d_in[0];
  const float* adj = (const float*)d_in[1];
  const int*   msk = (const int*)d_in[2];
  const float* Wq  = (const float*)d_in[3];
  const float* Wk  = (const float*)d_in[4];
  const float* Wv  = (const float*)d_in[5];
  const float* Wo  = (const float*)d_in[6];
  const float* W1  = (const float*)d_in[7];
  const float* b1  = (const float*)d_in[8];
  const float* W2  = (const float*)d_in[9];
  const float* b2  = (const float*)d_in[10];
  const float* g1  = (const float*)d_in[11];
  const float* be1 = (const float*)d_in[12];
  const float* g2  = (const float*)d_in[13];
  const float* be2 = (const float*)d_in[14];

  float* out  = (float*)d_out;
  float* mout = out + (size_t)8 * 1024 * 512;

  char* ws = (char*)d_ws;
  const size_t MB = 1024 * 1024;
  bf16_t* wqb = (bf16_t*)(ws);
  bf16_t* wkb = (bf16_t*)(ws + 512 * 1024);
  bf16_t* wvb = (bf16_t*)(ws + 1 * MB);
  bf16_t* wob = (bf16_t*)(ws + 3 * MB / 2);
  bf16_t* w1b = (bf16_t*)(ws + 2 * MB);
  bf16_t* w2b = (bf16_t*)(ws + 4 * MB);
  float*  crl  = (float*)(ws + 6 * MB + 256 * 1024); // 256 KB (C + log2 l)
  float*  kmax = (float*)(ws + 6 * MB + 768 * 1024); // 256 B
  bf16_t* xb   = (bf16_t*)(ws + 8 * MB);   // 8-16: x bf16; then ctx; then zb
  bf16_t* ctx  = xb;
  bf16_t* zb   = xb;
  bf16_t* qb   = (bf16_t*)(ws + 16 * MB);  // 16-24 (dead after attn_mean)
  bf16_t* kb   = (bf16_t*)(ws + 24 * MB);  // 24-32 (dead after attn_mean)
  bf16_t* vb   = (bf16_t*)(ws + 32 * MB);  // 32-40 (dead after vtrans)
  bf16_t* vT   = (bf16_t*)(ws + 40 * MB);  // 40-48 (dead after attn_ctx)
  float*  gout1 = (float*)(ws + 16 * MB);  // 16-48: 2x16MB f32 (wo split-K partials)
  bf16_t* hb    = (bf16_t*)(ws + 16 * MB); // 16-48 bf16 (ffn1 -> ffn2)
  float*  gout2 = (float*)(ws + 44 * MB);  // 44-76: 2x16MB f32 (ffn2 split-K partials)
  bf16_t* eadjP = (bf16_t*)(ws + 72 * MB); // 72-74 permuted exp(adj)*mask table
  // eadjP (72-74) overlaps gout2 split1 (60-76): eadjP is dead after attn_mean,
  // which completes before the ffn2 gemm writes gout2. Safe.

  // converts + eadj prep (one launch)
  k_cvtall<<<7424, 256, 0, stream>>>(x, Wq, Wk, Wv, Wo, W1, W2, adj, msk,
                                     xb, wqb, wkb, wvb, wob, w1b, w2b, eadjP);

  // QKV: one GEMM, N=1536 (wq|wk|wv contiguous); q pre-scaled by 0.125*log2e
  k_gemm<0, 1><<<64 * 12, 256, 0, stream>>>(xb, wqb, 512, 12, nullptr, qb, nullptr, 512);
  // v transpose + kmax in one launch
  k_vtrans_knorm<<<1088, 256, 0, stream>>>(vb, vT, kb, kmax);

  // attention: ctx (counted-vmcnt double-buffer pipeline) + crl, then mean
  k_attn_ctx<<<512, 512, 0, stream>>>(qb, kb, vT, eadjP, kmax, ctx, crl);
  k_attn_mean<<<1024, 256, 0, stream>>>(qb, kb, eadjP, crl, mout);

  // Wo proj (split-K x2) -> gout1[2]; residual(x f32) + LN1 -> zb (bf16)
  k_gemm<2, 2><<<2 * 64 * 4, 256, 0, stream>>>(ctx, wob, 512, 4, nullptr, nullptr, gout1, 512);
  k_resln<<<2048, 256, 0, stream>>>(gout1, 2, x, nullptr, g1, be1, nullptr, zb);
  // FFN1: relu(zb @ W1^T + b1) -> hb
  k_gemm<1, 1><<<64 * 16, 256, 0, stream>>>(zb, w1b, 512, 16, b1, hb, nullptr, 2048);
  // FFN2 (split-K x2) -> gout2[2]; residual(zb bf16) + LN2 -> out
  k_gemm<2, 2><<<2 * 64 * 4, 256, 0, stream>>>(hb, w2b, 2048, 4, b2, nullptr, gout2, 512);
  k_resln<<<2048, 256, 0, stream>>>(gout2, 2, nullptr, zb, g2, be2, out, nullptr);
}

// Round 14
// 218.172 us; speedup vs baseline: 1.1027x; 1.0477x over previous
//
#include <hip/hip_runtime.h>
#include <math.h>
#include <stdint.h>

// GraphTransformerLayer on MI355X (gfx950).
// B=8, N=1024, D=512, H=8, Dh=64, F=2048.
// Round 14: fix attn_mean epilogue eadjT indexing (needs 4x bf16x8 per lane:
//           group A pos 0-7/8-15, group B pos 0-7/8-15; elem (kg&1)*4+j).
//           Rest identical to round 13 (swapped-QK register-P attention).

using bf16_t = __bf16;
typedef __attribute__((__ext_vector_type__(8))) __bf16 bf16x8;
typedef __attribute__((__ext_vector_type__(4))) __bf16 bf16x4;
typedef __attribute__((__ext_vector_type__(4))) float  f32x4;

#define DEVI __device__ __forceinline__

DEVI f32x4 mfma16(bf16x8 a, bf16x8 b, f32x4 c) {
  return __builtin_amdgcn_mfma_f32_16x16x32_bf16(a, b, c, 0, 0, 0);
}

// async global->LDS, 16B per lane. dest = wave-uniform base (+ lane*16 by HW).
DEVI void gload_lds16(const void* g, void* l) {
  __builtin_amdgcn_global_load_lds(
      (const __attribute__((address_space(1))) uint32_t*)g,
      (__attribute__((address_space(3))) uint32_t*)l, 16, 0, 0);
}

#define EPSC  (1e-5f)
#define QSCALE 0.18033688f   // 0.125 * log2(e): scores come out of MFMA in base-2

// ---------------- fused converts: x (4096) + weights (3072) + eadj prep (256) ----------------
// eadj stored PERMUTED within each 64-col group: pos = g*16 + c*4 + j where
// k = c*16 + g*4 + j (g=(k>>2)&3, c=(k>>4)&3, j=k&3). Lane (q=l16, g) then
// reads its tile's 16 eadj values as one contiguous 32B run at offset g*16.
__global__ __launch_bounds__(256) void k_cvtall(const float* __restrict__ x,
                                                const float* __restrict__ wq,
                                                const float* __restrict__ wk,
                                                const float* __restrict__ wv,
                                                const float* __restrict__ wo,
                                                const float* __restrict__ w1,
                                                const float* __restrict__ w2,
                                                const float* __restrict__ adj,
                                                const int* __restrict__ msk,
                                                bf16_t* __restrict__ ox,
                                                bf16_t* __restrict__ owq,
                                                bf16_t* __restrict__ owk,
                                                bf16_t* __restrict__ owv,
                                                bf16_t* __restrict__ owo,
                                                bf16_t* __restrict__ ow1,
                                                bf16_t* __restrict__ ow2,
                                                bf16_t* __restrict__ eadjT) {
  int blk = blockIdx.x;
  if (blk >= 7168) {  // eadj prep: 256 blocks x 4 rows
    int row  = (blk - 7168) * 4 + (threadIdx.x >> 6);
    int lane = threadIdx.x & 63;
    for (int i = 0; i < 16; i++) {
      int c = lane + 64 * i;
      size_t idx = (size_t)row * 1024 + c;
      float a = adj[idx];
      bool valid = (msk[idx] != 0);
      int pos = (c & ~63) + (((c >> 2) & 3) << 4) + (((c >> 4) & 3) << 2) + (c & 3);
      eadjT[(size_t)row * 1024 + pos] = valid ? (__bf16)__expf(a) : (__bf16)0.f;
    }
    return;
  }
  const float* src; bf16_t* dst; int base;
  if (blk < 4096)      { src = x;  dst = ox;  base = blk; }
  else {
    blk -= 4096;
    if      (blk < 256)  { src = wq; dst = owq; base = blk; }
    else if (blk < 512)  { src = wk; dst = owk; base = blk - 256; }
    else if (blk < 768)  { src = wv; dst = owv; base = blk - 512; }
    else if (blk < 1024) { src = wo; dst = owo; base = blk - 768; }
    else if (blk < 2048) { src = w1; dst = ow1; base = blk - 1024; }
    else                 { src = w2; dst = ow2; base = blk - 2048; }
  }
  int i = base * 256 + threadIdx.x;
  float4 v = ((const float4*)src)[i];
  bf16x4 o = { (__bf16)v.x, (__bf16)v.y, (__bf16)v.z, (__bf16)v.w };
  ((bf16x4*)dst)[i] = o;
}

// ---------------- tiled GEMM: C[8192 x N] = A[8192 x K] @ B[N x K]^T ----------------
// 128x128 tile, 4 waves (2x2), each wave 64x64 (4x4 fragments). BK=32.
// NSPLIT>1: K split into NSPLIT slices; slice s writes outf + s*8192*out_ncols.
template<int EPI, int NSPLIT>
__global__ __launch_bounds__(256) void k_gemm(const bf16_t* __restrict__ A,
                                              const bf16_t* __restrict__ B,
                                              int K, int nbx,
                                              const float* __restrict__ bias,
                                              bf16_t* __restrict__ outb,
                                              float* __restrict__ outf,
                                              int out_ncols) {
  __shared__ bf16_t lA[2][4096];
  __shared__ bf16_t lB[2][4096];
  int bid = blockIdx.x;
  int bps = 64 * nbx;                 // blocks per split (M/128 = 64)
  int split = bid / bps, r = bid - split * bps;
  int nb = r % nbx, mb = r / nbx;
  int KS = K / NSPLIT;
  const bf16_t* Ab = A + (size_t)split * KS;
  const bf16_t* Bb = B + (size_t)split * KS;
  int tid = threadIdx.x, wid = tid >> 6, lane = tid & 63;
  int l16 = lane & 15, g = lane >> 4;
  int wr = wid >> 1, wc = wid & 1;
  int rowbase = mb * 128, c0 = nb * 128;

  int dA0 = wid * 2048 + lane * 16;
  int rA0 = dA0 >> 6;
  int cbA = ((dA0 >> 4) & 3) ^ (rA0 & 3);
  const bf16_t* Asrc0 = Ab + (size_t)(rowbase + rA0) * K + cbA * 8;
  const bf16_t* Asrc1 = Ab + (size_t)(rowbase + rA0 + 16) * K + cbA * 8;
  const bf16_t* Bsrc0 = Bb + (size_t)(c0 + rA0) * K + cbA * 8;
  const bf16_t* Bsrc1 = Bb + (size_t)(c0 + rA0 + 16) * K + cbA * 8;

  f32x4 acc[4][4];
#pragma unroll
  for (int m = 0; m < 4; m++)
#pragma unroll
    for (int n = 0; n < 4; n++) acc[m][n] = (f32x4){0.f, 0.f, 0.f, 0.f};

  gload_lds16(Asrc0, (char*)&lA[0][0] + wid * 2048);
  gload_lds16(Asrc1, (char*)&lA[0][0] + wid * 2048 + 1024);
  gload_lds16(Bsrc0, (char*)&lB[0][0] + wid * 2048);
  gload_lds16(Bsrc1, (char*)&lB[0][0] + wid * 2048 + 1024);
  __syncthreads();

  for (int k0 = 0; k0 < KS; k0 += 32) {
    int buf = (k0 >> 5) & 1;
    if (k0 + 32 < KS) {
      gload_lds16(Asrc0 + k0 + 32, (char*)&lA[buf ^ 1][0] + wid * 2048);
      gload_lds16(Asrc1 + k0 + 32, (char*)&lA[buf ^ 1][0] + wid * 2048 + 1024);
      gload_lds16(Bsrc0 + k0 + 32, (char*)&lB[buf ^ 1][0] + wid * 2048);
      gload_lds16(Bsrc1 + k0 + 32, (char*)&lB[buf ^ 1][0] + wid * 2048 + 1024);
    }
    const char* cA = (const char*)&lA[buf][0];
    const char* cB = (const char*)&lB[buf][0];
    bf16x8 af[4], bq[4];
#pragma unroll
    for (int m = 0; m < 4; m++) {
      int row = wr * 64 + m * 16 + l16;
      af[m] = *(const bf16x8*)(cA + row * 64 + ((g ^ (row & 3)) << 4));
    }
#pragma unroll
    for (int n = 0; n < 4; n++) {
      int row = wc * 64 + n * 16 + l16;
      bq[n] = *(const bf16x8*)(cB + row * 64 + ((g ^ (row & 3)) << 4));
    }
#pragma unroll
    for (int m = 0; m < 4; m++)
#pragma unroll
      for (int n = 0; n < 4; n++) acc[m][n] = mfma16(af[m], bq[n], acc[m][n]);
    __syncthreads();
  }

  int which = c0 / out_ncols;
  int cloc0 = c0 - which * out_ncols;
  size_t obase = (size_t)which * 8192 * out_ncols +
                 (size_t)split * 8192 * out_ncols * (NSPLIT > 1 ? 1 : 0);
  float osc = (EPI == 0 && which == 0) ? QSCALE : 1.0f;  // q pre-scale (base-2)
#pragma unroll
  for (int n = 0; n < 4; n++) {
    int col = cloc0 + wc * 64 + n * 16 + l16;
    float bv = (EPI >= 1 && bias && split == 0) ? bias[col] : 0.f;
#pragma unroll
    for (int m = 0; m < 4; m++)
#pragma unroll
      for (int j = 0; j < 4; j++) {
        int row = rowbase + wr * 64 + m * 16 + g * 4 + j;
        float v = acc[m][n][j] + bv;
        size_t idx = obase + (size_t)row * out_ncols + col;
        if (EPI == 1) outb[idx] = (__bf16)fmaxf(v, 0.f);
        else if (EPI == 0) outb[idx] = (__bf16)(v * osc);
        else outf[idx] = v;
      }
  }
}

// ---------------- residual + LayerNorm: sums nsplit f32 partials ----------------
__global__ __launch_bounds__(256) void k_resln(const float* __restrict__ gin,
                                               int nsplit,
                                               const float* __restrict__ residf,
                                               const bf16_t* __restrict__ residb,
                                               const float* __restrict__ gam,
                                               const float* __restrict__ bet,
                                               float* __restrict__ outf,
                                               bf16_t* __restrict__ outb) {
  const size_t GS = (size_t)8192 * 512;
  int row = blockIdx.x * 4 + (threadIdx.x >> 6);
  int lane = threadIdx.x & 63;
  const float* gp = gin + (size_t)row * 512;
  float4 a0 = ((const float4*)gp)[lane];
  float4 a1 = ((const float4*)gp)[lane + 64];
  for (int s = 1; s < nsplit; s++) {
    const float* gp2 = gp + s * GS;
    float4 r0 = ((const float4*)gp2)[lane];
    float4 r1 = ((const float4*)gp2)[lane + 64];
    a0.x += r0.x; a0.y += r0.y; a0.z += r0.z; a0.w += r0.w;
    a1.x += r1.x; a1.y += r1.y; a1.z += r1.z; a1.w += r1.w;
  }
  if (residf) {
    const float* rp = residf + (size_t)row * 512;
    float4 r0 = ((const float4*)rp)[lane];
    float4 r1 = ((const float4*)rp)[lane + 64];
    a0.x += r0.x; a0.y += r0.y; a0.z += r0.z; a0.w += r0.w;
    a1.x += r1.x; a1.y += r1.y; a1.z += r1.z; a1.w += r1.w;
  } else {
    const bf16_t* rp = residb + (size_t)row * 512;
    bf16x4 r0 = ((const bf16x4*)rp)[lane];
    bf16x4 r1 = ((const bf16x4*)rp)[lane + 64];
    a0.x += (float)r0[0]; a0.y += (float)r0[1]; a0.z += (float)r0[2]; a0.w += (float)r0[3];
    a1.x += (float)r1[0]; a1.y += (float)r1[1]; a1.z += (float)r1[2]; a1.w += (float)r1[3];
  }
  float s = a0.x + a0.y + a0.z + a0.w + a1.x + a1.y + a1.z + a1.w;
  for (int off = 1; off < 64; off <<= 1) s += __shfl_xor(s, off);
  float mu = s * (1.f / 512.f);
  float sq = (a0.x - mu) * (a0.x - mu) + (a0.y - mu) * (a0.y - mu) +
             (a0.z - mu) * (a0.z - mu) + (a0.w - mu) * (a0.w - mu) +
             (a1.x - mu) * (a1.x - mu) + (a1.y - mu) * (a1.y - mu) +
             (a1.z - mu) * (a1.z - mu) + (a1.w - mu) * (a1.w - mu);
  for (int off = 1; off < 64; off <<= 1) sq += __shfl_xor(sq, off);
  float rs = rsqrtf(sq * (1.f / 512.f) + EPSC);

  float4 g0 = ((const float4*)gam)[lane], g1v = ((const float4*)gam)[lane + 64];
  float4 b0 = ((const float4*)bet)[lane], b1v = ((const float4*)bet)[lane + 64];
  float4 o0, o1;
  o0.x = (a0.x - mu) * rs * g0.x + b0.x;  o0.y = (a0.y - mu) * rs * g0.y + b0.y;
  o0.z = (a0.z - mu) * rs * g0.z + b0.z;  o0.w = (a0.w - mu) * rs * g0.w + b0.w;
  o1.x = (a1.x - mu) * rs * g1v.x + b1v.x; o1.y = (a1.y - mu) * rs * g1v.y + b1v.y;
  o1.z = (a1.z - mu) * rs * g1v.z + b1v.z; o1.w = (a1.w - mu) * rs * g1v.w + b1v.w;
  if (outf) {
    float* op = outf + (size_t)row * 512;
    ((float4*)op)[lane] = o0;
    ((float4*)op)[lane + 64] = o1;
  }
  if (outb) {
    bf16_t* op = outb + (size_t)row * 512;
    bf16x4 q0 = { (__bf16)o0.x, (__bf16)o0.y, (__bf16)o0.z, (__bf16)o0.w };
    bf16x4 q1 = { (__bf16)o1.x, (__bf16)o1.y, (__bf16)o1.z, (__bf16)o1.w };
    ((bf16x4*)op)[lane] = q0;
    ((bf16x4*)op)[lane + 64] = q1;
  }
}

// ---------------- v transpose (blk<1024, k-permuted) + kmax (blk>=1024) ----------------
// vT column written at pi(k) = (k&32) + ((k>>2)&3)*8 + ((k>>4)&1)*4 + (k&3):
// matches the PV A-fragment slot order of the register-built P operand.
__global__ __launch_bounds__(256) void k_vtrans_knorm(const bf16_t* __restrict__ v,
                                                      bf16_t* __restrict__ vT,
                                                      const bf16_t* __restrict__ kk,
                                                      float* __restrict__ kmax) {
  __shared__ bf16_t t[64 * 66];
  __shared__ float red[4];
  int bid = blockIdx.x;
  int tid = threadIdx.x, wid = tid >> 6, lane = tid & 63;
  if (bid < 1024) {
    int nt = bid & 15, h = (bid >> 4) & 7, b = bid >> 7;
    for (int i = 0; i < 16; i++) {
      int n = wid * 16 + i;
      t[lane * 66 + n] = v[(size_t)(b * 1024 + nt * 64 + n) * 512 + h * 64 + lane];
    }
    __syncthreads();
    int pi = (lane & 32) + (((lane >> 2) & 3) << 3) + (((lane >> 4) & 1) << 2) + (lane & 3);
    for (int i = 0; i < 16; i++) {
      int d = wid * 16 + i;
      vT[(size_t)((b * 8 + h) * 64 + d) * 1024 + nt * 64 + pi] = t[d * 66 + lane];
    }
  } else {
    int bh = bid - 1024;
    int b = bh >> 3, h = bh & 7;
    float mx = 0.f;
    for (int n = tid; n < 1024; n += 256) {
      const bf16_t* kp = kk + (size_t)(b * 1024 + n) * 512 + h * 64;
      float ss = 0.f;
#pragma unroll
      for (int vv = 0; vv < 8; vv++) {
        bf16x8 kv = *(const bf16x8*)(kp + vv * 8);
#pragma unroll
        for (int e = 0; e < 8; e++) { float f = (float)kv[e]; ss += f * f; }
      }
      mx = fmaxf(mx, ss);
    }
    for (int off = 1; off < 64; off <<= 1) mx = fmaxf(mx, __shfl_xor(mx, off));
    if (lane == 0) red[wid] = mx;
    __syncthreads();
    if (tid == 0) kmax[bh] = sqrtf(fmaxf(fmaxf(red[0], red[1]), fmaxf(red[2], red[3])));
  }
}

// ---------------- attention: ctx (normalized) + crl = C + log2(l) ----------------
// grid 512: bid = qt*64 + (h + 8b). Block: 512 threads (8 waves x 16 q = 128 q),
// full k = 16 tiles of 64. SWAPPED QK: s = mfma(K,Q) -> lane (l16,g) holds p
// for q=l16, k=cg*16+g*4+j. P cast to bf16 in-register feeds PV directly
// (V tile k-permuted by pi at vtrans). No LDS p buffer. Counted barrier:
// vmcnt(2) lgkmcnt(0) + raw s_barrier (stage's 2 loads oldest of 4).
__global__ __launch_bounds__(512) void k_attn_ctx(const bf16_t* __restrict__ q,
                                                  const bf16_t* __restrict__ kk,
                                                  const bf16_t* __restrict__ vT,
                                                  const bf16_t* __restrict__ eadjT,
                                                  const float* __restrict__ kmax,
                                                  bf16_t* __restrict__ ctx,
                                                  float* __restrict__ crl) {
  __shared__ bf16_t ldsK[2][4096];
  __shared__ bf16_t ldsV[2][4096];
  int bid = blockIdx.x;
  int qt = bid >> 6, h = bid & 7, b = (bid >> 3) & 7;
  int tid = threadIdx.x, wid = tid >> 6, lane = tid & 63;
  int l16 = lane & 15, g = lane >> 4;
  int qg0 = qt * 128 + wid * 16;
  int kvbase = (b * 8 + h) * 64;

  int d0 = wid * 1024 + lane * 16;
  int row0 = d0 >> 7;
  int cb0 = ((d0 >> 4) & 7) ^ (row0 & 7);
  const bf16_t* ksrc = kk + (size_t)(b * 1024) * 512 + h * 64;
  const bf16_t* vsrc = vT + (size_t)kvbase * 1024;

  auto stage = [&](int buf, int kc0) {
    gload_lds16(ksrc + (size_t)(kc0 + row0) * 512 + cb0 * 8, &ldsK[buf][wid * 512]);
    gload_lds16(vsrc + (size_t)row0 * 1024 + kc0 + cb0 * 8, &ldsV[buf][wid * 512]);
  };

  const bf16_t* qp = q + (size_t)(b * 1024 + qg0 + l16) * 512 + h * 64 + 8 * g;
  bf16x8 aq0 = *(const bf16x8*)qp;
  bf16x8 aq1 = *(const bf16x8*)(qp + 32);

  // C = |q'| * kmax (per lane: own q-row l16)
  float kmaxv = kmax[b * 8 + h];
  float ssq = 0.f;
#pragma unroll
  for (int e = 0; e < 8; e++) {
    float f0 = (float)aq0[e], f1 = (float)aq1[e];
    ssq += f0 * f0 + f1 * f1;
  }
  ssq += __shfl_xor(ssq, 16);
  ssq += __shfl_xor(ssq, 32);
  float Cn = sqrtf(ssq) * kmaxv;
  f32x4 negC4 = (f32x4){-Cn, -Cn, -Cn, -Cn};

  f32x4 cacc[4];
#pragma unroll
  for (int d = 0; d < 4; d++) cacc[d] = (f32x4){0.f, 0.f, 0.f, 0.f};
  float ls = 0.f;
  int rph = l16 & 7;
  // eadjT: lane's 16 values for a 64-k group are contiguous at row*1024 + kc0 + g*16
  const bf16_t* erowT = eadjT + (size_t)(qg0 + l16) * 1024 + g * 16;

  bf16x8 eaA[2], eaB[2];
  auto loadEA = [&](bf16x8 (&d)[2], int kc0) {
    d[0] = *(const bf16x8*)(erowT + kc0);       // cg 0,1 (elems (cg&1)*4+j)
    d[1] = *(const bf16x8*)(erowT + kc0 + 8);   // cg 2,3
  };

  auto cbar = [&]() {
    __builtin_amdgcn_sched_barrier(0);
    asm volatile("s_waitcnt vmcnt(2) lgkmcnt(0)" ::: "memory");
    __builtin_amdgcn_sched_barrier(0);
    __builtin_amdgcn_s_barrier();
    __builtin_amdgcn_sched_barrier(0);
  };

  auto tile = [&](int kt, int buf, bf16x8 (&eaC)[2], bf16x8 (&eaN)[2]) {
    int ktn = (kt + 1 < 16) ? kt + 1 : 15;   // clamped tail keeps counts uniform
    stage(buf ^ 1, ktn * 64);                // 2 loads (oldest outstanding)
    loadEA(eaN, ktn * 64);                   // 2 loads

    const char* curK = (const char*)ldsK[buf];
    const char* curV = (const char*)ldsV[buf];

    bf16x8 pa0, pa1;
#pragma unroll
    for (int cg = 0; cg < 4; cg++) {
      const char* krow = curK + ((cg * 16 + l16) << 7);
      bf16x8 k0 = *(const bf16x8*)(krow + ((g ^ rph) << 4));
      bf16x8 k1 = *(const bf16x8*)(krow + (((g + 4) ^ rph) << 4));
      __builtin_amdgcn_s_setprio(1);
      f32x4 s = mfma16(k0, aq0, negC4);     // SWAPPED: A=K, B=Q -> col=q=l16
      s = mfma16(k1, aq1, s);
      __builtin_amdgcn_s_setprio(0);
#pragma unroll
      for (int j = 0; j < 4; j++) {
        float p = (float)eaC[cg >> 1][(cg & 1) * 4 + j] * exp2f(s[j]);
        ls += p;
        if (cg < 2) pa0[cg * 4 + j] = (__bf16)p;
        else        pa1[(cg - 2) * 4 + j] = (__bf16)p;
      }
    }
#pragma unroll
    for (int half = 0; half < 2; half++) {
      bf16x8 pa = half ? pa1 : pa0;
      __builtin_amdgcn_s_setprio(1);
#pragma unroll
      for (int dg = 0; dg < 4; dg++) {
        const char* vrow = curV + ((dg * 16 + l16) << 7);
        bf16x8 vv = *(const bf16x8*)(vrow + (((g + half * 4) ^ rph) << 4));
        cacc[dg] = mfma16(pa, vv, cacc[dg]);
      }
      __builtin_amdgcn_s_setprio(0);
    }
    cbar();
  };

  // prologue
  stage(0, 0);
  loadEA(eaA, 0);
  cbar();

  for (int k2 = 0; k2 < 8; k2++) {
    tile(2 * k2,     0, eaA, eaB);
    tile(2 * k2 + 1, 1, eaB, eaA);
  }

  // ls per lane covers k subsets per g; sum across g-replicas
  ls += __shfl_xor(ls, 16);
  ls += __shfl_xor(ls, 32);
  float rcv = (ls > 0.f) ? (1.f / ls) : 0.f;
  float rcj[4];
#pragma unroll
  for (int j = 0; j < 4; j++) rcj[j] = __shfl(rcv, g * 4 + j);

#pragma unroll
  for (int dg = 0; dg < 4; dg++)
#pragma unroll
    for (int j = 0; j < 4; j++) {
      int row = qg0 + g * 4 + j;
      ctx[(size_t)(b * 1024 + row) * 512 + h * 64 + dg * 16 + l16] =
          (__bf16)(cacc[dg][j] * rcj[j]);
    }
  if (lane < 16) {
    int li = (b * 8 + h) * 1024 + qg0 + lane;
    crl[li] = (ls > 0.f) ? (Cn + __log2f(ls)) : 1.0e30f;
  }
}

// ---------------- attention mean over heads -> mout (barrier-free, swapped QK) ----------------
// mean = eadj * (1/8) * sum_h exp2(s_h - crl_h); lane (l16,g): q=l16, k in regs.
__global__ __launch_bounds__(256, 4) void k_attn_mean(const bf16_t* __restrict__ q,
                                                      const bf16_t* __restrict__ kk,
                                                      const bf16_t* __restrict__ eadjT,
                                                      const float* __restrict__ crl,
                                                      float* __restrict__ mout) {
  __shared__ bf16_t lds[4][2][2048];   // [wave][buf][4KB]
  int bid = blockIdx.x;
  int kq = bid & 7, qt = (bid >> 3) & 15, b = bid >> 7;
  int tid = threadIdx.x, wid = tid >> 6, lane = tid & 63;
  int l16 = lane & 15, g = lane >> 4;
  int qg0 = qt * 64 + wid * 16;
  int kbase = kq * 128;
  int rl = lane >> 3;
  int cb = (lane & 7) ^ rl;
  const bf16_t* ksrc = kk + (size_t)(b * 1024 + kbase) * 512;

  auto stage = [&](int t) {
    int h = t >> 2, c = t & 3;
    char* dst = (char*)&lds[wid][t & 1][0];
    const bf16_t* sp = ksrc + (size_t)(c * 32 + rl) * 512 + h * 64 + cb * 8;
#pragma unroll
    for (int i = 0; i < 4; i++)
      gload_lds16(sp + (size_t)i * 8 * 512, dst + i * 1024);
  };

  f32x4 macc[8];
#pragma unroll
  for (int kg = 0; kg < 8; kg++) macc[kg] = (f32x4){0.f, 0.f, 0.f, 0.f};

  stage(0);

  for (int h = 0; h < 8; h++) {
    const bf16_t* qp = q + (size_t)(b * 1024 + qg0 + l16) * 512 + h * 64 + 8 * g;
    bf16x8 aq0 = *(const bf16x8*)qp;
    bf16x8 aq1 = *(const bf16x8*)(qp + 32);
    float CRs = crl[(b * 8 + h) * 1024 + qg0 + l16];   // own q-row
    f32x4 negCR4 = (f32x4){-CRs, -CRs, -CRs, -CRs};
#pragma unroll
    for (int c = 0; c < 4; c++) {
      int t = h * 4 + c;
      __builtin_amdgcn_sched_barrier(0);
      if (t < 31) {
        stage(t + 1);
        __builtin_amdgcn_sched_barrier(0);
        asm volatile("s_waitcnt vmcnt(4)" ::: "memory");
      } else {
        asm volatile("s_waitcnt vmcnt(0)" ::: "memory");
      }
      __builtin_amdgcn_sched_barrier(0);
      const char* cK = (const char*)&lds[wid][t & 1][0];
#pragma unroll
      for (int cg = 0; cg < 2; cg++) {
        const char* krow = cK + ((cg * 16 + l16) << 7);
        bf16x8 k0 = *(const bf16x8*)(krow + ((g ^ (l16 & 7)) << 4));
        bf16x8 k1 = *(const bf16x8*)(krow + (((g + 4) ^ (l16 & 7)) << 4));
        __builtin_amdgcn_s_setprio(1);
        f32x4 s = mfma16(k0, aq0, negCR4);   // SWAPPED
        s = mfma16(k1, aq1, s);
        __builtin_amdgcn_s_setprio(0);
        int kg = c * 2 + cg;
#pragma unroll
        for (int j = 0; j < 4; j++)
          macc[kg][j] += exp2f(s[j]);
      }
    }
  }

  // epilogue: k = kbase + kg*16 + g*4 + j for q = l16. eadjT per 64-group:
  // lane's 16 values contiguous at row*1024 + group + g*16; within them,
  // value for k-subblock c' (= kg within group) at elem c'*4 + j.
  // kg 0..3 -> group A (offset 0), c'=kg; kg 4..7 -> group B (offset 64), c'=kg-4.
  const bf16_t* erowT = eadjT + (size_t)(qg0 + l16) * 1024 + kbase + g * 16;
  bf16x8 eA0 = *(const bf16x8*)(erowT);        // group A, c' 0,1
  bf16x8 eA1 = *(const bf16x8*)(erowT + 8);    // group A, c' 2,3
  bf16x8 eB0 = *(const bf16x8*)(erowT + 64);   // group B, c' 0,1
  bf16x8 eB1 = *(const bf16x8*)(erowT + 72);   // group B, c' 2,3
  float* mrow = mout + (size_t)b * 1048576 + (size_t)(qg0 + l16) * 1024 + kbase;
#pragma unroll
  for (int kg = 0; kg < 8; kg++) {
    bf16x8 eg = (kg < 2) ? eA0 : (kg < 4) ? eA1 : (kg < 6) ? eB0 : eB1;
    f32x4 mv;
#pragma unroll
    for (int j = 0; j < 4; j++)
      mv[j] = macc[kg][j] * (float)eg[(kg & 1) * 4 + j] * 0.125f;
    *(f32x4*)(mrow + kg * 16 + g * 4) = mv;
  }
}

extern "C" void kernel_launch(void* const* d_in, const int* in_sizes, int n_in,
                              void* d_out, int out_size, void* d_ws, size_t ws_size,
                              hipStream_t stream) {
  (void)in_sizes; (void)n_in; (void)out_size; (void)ws_size;
  const float* x   = (const float*)d_in[0];
  const float* adj = (const float*)d_in[1];
  const int*   msk = (const int*)d_in[2];
  const float* Wq  = (const float*)d_in[3];
  const float* Wk  = (const float*)d_in[4];
  const float* Wv  = (const float*)d_in[5];
  const float* Wo  = (const float*)d_in[6];
  const float* W1  = (const float*)d_in[7];
  const float* b1  = (const float*)d_in[8];
  const float* W2  = (const float*)d_in[9];
  const float* b2  = (const float*)d_in[10];
  const float* g1  = (const float*)d_in[11];
  const float* be1 = (const float*)d_in[12];
  const float* g2  = (const float*)d_in[13];
  const float* be2 = (const float*)d_in[14];

  float* out  = (float*)d_out;
  float* mout = out + (size_t)8 * 1024 * 512;

  char* ws = (char*)d_ws;
  const size_t MB = 1024 * 1024;
  bf16_t* wqb = (bf16_t*)(ws);
  bf16_t* wkb = (bf16_t*)(ws + 512 * 1024);
  bf16_t* wvb = (bf16_t*)(ws + 1 * MB);
  bf16_t* wob = (bf16_t*)(ws + 3 * MB / 2);
  bf16_t* w1b = (bf16_t*)(ws + 2 * MB);
  bf16_t* w2b = (bf16_t*)(ws + 4 * MB);
  float*  crl  = (float*)(ws + 6 * MB + 256 * 1024); // 256 KB (C + log2 l)
  float*  kmax = (float*)(ws + 6 * MB + 768 * 1024); // 256 B
  bf16_t* xb   = (bf16_t*)(ws + 8 * MB);   // 8-16: x bf16; then ctx; then zb
  bf16_t* ctx  = xb;
  bf16_t* zb   = xb;
  bf16_t* qb   = (bf16_t*)(ws + 16 * MB);  // 16-24 (dead after attn_mean)
  bf16_t* kb   = (bf16_t*)(ws + 24 * MB);  // 24-32 (dead after attn_mean)
  bf16_t* vb   = (bf16_t*)(ws + 32 * MB);  // 32-40 (dead after vtrans)
  bf16_t* vT   = (bf16_t*)(ws + 40 * MB);  // 40-48 (dead after attn_ctx)
  float*  gout1 = (float*)(ws + 16 * MB);  // 16-48: 2x16MB f32 (wo split-K partials)
  bf16_t* hb    = (bf16_t*)(ws + 16 * MB); // 16-48 bf16 (ffn1 -> ffn2)
  float*  gout2 = (float*)(ws + 44 * MB);  // 44-76: 2x16MB f32 (ffn2 split-K partials)
  bf16_t* eadjT = (bf16_t*)(ws + 72 * MB); // 72-74 permuted exp(adj)*mask table
  // eadjT (72-74) overlaps gout2 split1 (60-76): eadjT is dead after attn_mean,
  // which completes before the ffn2 gemm writes gout2. Safe.

  // converts + eadj prep (one launch)
  k_cvtall<<<7424, 256, 0, stream>>>(x, Wq, Wk, Wv, Wo, W1, W2, adj, msk,
                                     xb, wqb, wkb, wvb, wob, w1b, w2b, eadjT);

  // QKV: one GEMM, N=1536 (wq|wk|wv contiguous); q pre-scaled by 0.125*log2e
  k_gemm<0, 1><<<64 * 12, 256, 0, stream>>>(xb, wqb, 512, 12, nullptr, qb, nullptr, 512);
  // v transpose (k-permuted) + kmax in one launch
  k_vtrans_knorm<<<1088, 256, 0, stream>>>(vb, vT, kb, kmax);

  // attention: ctx (swapped-QK register-P pipeline) + crl, then mean
  k_attn_ctx<<<512, 512, 0, stream>>>(qb, kb, vT, eadjT, kmax, ctx, crl);
  k_attn_mean<<<1024, 256, 0, stream>>>(qb, kb, eadjT, crl, mout);

  // Wo proj (split-K x2) -> gout1[2]; residual(x f32) + LN1 -> zb (bf16)
  k_gemm<2, 2><<<2 * 64 * 4, 256, 0, stream>>>(ctx, wob, 512, 4, nullptr, nullptr, gout1, 512);
  k_resln<<<2048, 256, 0, stream>>>(gout1, 2, x, nullptr, g1, be1, nullptr, zb);
  // FFN1: relu(zb @ W1^T + b1) -> hb
  k_gemm<1, 1><<<64 * 16, 256, 0, stream>>>(zb, w1b, 512, 16, b1, hb, nullptr, 2048);
  // FFN2 (split-K x2) -> gout2[2]; residual(zb bf16) + LN2 -> out
  k_gemm<2, 2><<<2 * 64 * 4, 256, 0, stream>>>(hb, w2b, 2048, 4, b2, nullptr, gout2, 512);
  k_resln<<<2048, 256, 0, stream>>>(gout2, 2, nullptr, zb, g2, be2, out, nullptr);
}

// Round 15
// 218.079 us; speedup vs baseline: 1.1031x; 1.0004x over previous
//
#include <hip/hip_runtime.h>
#include <math.h>
#include <stdint.h>

// GraphTransformerLayer on MI355X (gfx950).
// B=8, N=1024, D=512, H=8, Dh=64, F=2048.
// Round 15: attn_ctx softmax row-sum moved onto the MFMA pipe (ls via
//           mfma(pa, ones) -> lsacc in accumulator layout; deletes 16 VALU
//           adds/lane/tile + cross-lane reduce + rcj shuffles). Rest = r14.

using bf16_t = __bf16;
typedef __attribute__((__ext_vector_type__(8))) __bf16 bf16x8;
typedef __attribute__((__ext_vector_type__(4))) __bf16 bf16x4;
typedef __attribute__((__ext_vector_type__(4))) float  f32x4;

#define DEVI __device__ __forceinline__

DEVI f32x4 mfma16(bf16x8 a, bf16x8 b, f32x4 c) {
  return __builtin_amdgcn_mfma_f32_16x16x32_bf16(a, b, c, 0, 0, 0);
}

// async global->LDS, 16B per lane. dest = wave-uniform base (+ lane*16 by HW).
DEVI void gload_lds16(const void* g, void* l) {
  __builtin_amdgcn_global_load_lds(
      (const __attribute__((address_space(1))) uint32_t*)g,
      (__attribute__((address_space(3))) uint32_t*)l, 16, 0, 0);
}

#define EPSC  (1e-5f)
#define QSCALE 0.18033688f   // 0.125 * log2(e): scores come out of MFMA in base-2

// ---------------- fused converts: x (4096) + weights (3072) + eadj prep (256) ----------------
// eadj stored PERMUTED within each 64-col group: pos = g*16 + c*4 + j where
// k = c*16 + g*4 + j (g=(k>>2)&3, c=(k>>4)&3, j=k&3).
__global__ __launch_bounds__(256) void k_cvtall(const float* __restrict__ x,
                                                const float* __restrict__ wq,
                                                const float* __restrict__ wk,
                                                const float* __restrict__ wv,
                                                const float* __restrict__ wo,
                                                const float* __restrict__ w1,
                                                const float* __restrict__ w2,
                                                const float* __restrict__ adj,
                                                const int* __restrict__ msk,
                                                bf16_t* __restrict__ ox,
                                                bf16_t* __restrict__ owq,
                                                bf16_t* __restrict__ owk,
                                                bf16_t* __restrict__ owv,
                                                bf16_t* __restrict__ owo,
                                                bf16_t* __restrict__ ow1,
                                                bf16_t* __restrict__ ow2,
                                                bf16_t* __restrict__ eadjT) {
  int blk = blockIdx.x;
  if (blk >= 7168) {  // eadj prep: 256 blocks x 4 rows
    int row  = (blk - 7168) * 4 + (threadIdx.x >> 6);
    int lane = threadIdx.x & 63;
    for (int i = 0; i < 16; i++) {
      int c = lane + 64 * i;
      size_t idx = (size_t)row * 1024 + c;
      float a = adj[idx];
      bool valid = (msk[idx] != 0);
      int pos = (c & ~63) + (((c >> 2) & 3) << 4) + (((c >> 4) & 3) << 2) + (c & 3);
      eadjT[(size_t)row * 1024 + pos] = valid ? (__bf16)__expf(a) : (__bf16)0.f;
    }
    return;
  }
  const float* src; bf16_t* dst; int base;
  if (blk < 4096)      { src = x;  dst = ox;  base = blk; }
  else {
    blk -= 4096;
    if      (blk < 256)  { src = wq; dst = owq; base = blk; }
    else if (blk < 512)  { src = wk; dst = owk; base = blk - 256; }
    else if (blk < 768)  { src = wv; dst = owv; base = blk - 512; }
    else if (blk < 1024) { src = wo; dst = owo; base = blk - 768; }
    else if (blk < 2048) { src = w1; dst = ow1; base = blk - 1024; }
    else                 { src = w2; dst = ow2; base = blk - 2048; }
  }
  int i = base * 256 + threadIdx.x;
  float4 v = ((const float4*)src)[i];
  bf16x4 o = { (__bf16)v.x, (__bf16)v.y, (__bf16)v.z, (__bf16)v.w };
  ((bf16x4*)dst)[i] = o;
}

// ---------------- tiled GEMM: C[8192 x N] = A[8192 x K] @ B[N x K]^T ----------------
template<int EPI, int NSPLIT>
__global__ __launch_bounds__(256) void k_gemm(const bf16_t* __restrict__ A,
                                              const bf16_t* __restrict__ B,
                                              int K, int nbx,
                                              const float* __restrict__ bias,
                                              bf16_t* __restrict__ outb,
                                              float* __restrict__ outf,
                                              int out_ncols) {
  __shared__ bf16_t lA[2][4096];
  __shared__ bf16_t lB[2][4096];
  int bid = blockIdx.x;
  int bps = 64 * nbx;
  int split = bid / bps, r = bid - split * bps;
  int nb = r % nbx, mb = r / nbx;
  int KS = K / NSPLIT;
  const bf16_t* Ab = A + (size_t)split * KS;
  const bf16_t* Bb = B + (size_t)split * KS;
  int tid = threadIdx.x, wid = tid >> 6, lane = tid & 63;
  int l16 = lane & 15, g = lane >> 4;
  int wr = wid >> 1, wc = wid & 1;
  int rowbase = mb * 128, c0 = nb * 128;

  int dA0 = wid * 2048 + lane * 16;
  int rA0 = dA0 >> 6;
  int cbA = ((dA0 >> 4) & 3) ^ (rA0 & 3);
  const bf16_t* Asrc0 = Ab + (size_t)(rowbase + rA0) * K + cbA * 8;
  const bf16_t* Asrc1 = Ab + (size_t)(rowbase + rA0 + 16) * K + cbA * 8;
  const bf16_t* Bsrc0 = Bb + (size_t)(c0 + rA0) * K + cbA * 8;
  const bf16_t* Bsrc1 = Bb + (size_t)(c0 + rA0 + 16) * K + cbA * 8;

  f32x4 acc[4][4];
#pragma unroll
  for (int m = 0; m < 4; m++)
#pragma unroll
    for (int n = 0; n < 4; n++) acc[m][n] = (f32x4){0.f, 0.f, 0.f, 0.f};

  gload_lds16(Asrc0, (char*)&lA[0][0] + wid * 2048);
  gload_lds16(Asrc1, (char*)&lA[0][0] + wid * 2048 + 1024);
  gload_lds16(Bsrc0, (char*)&lB[0][0] + wid * 2048);
  gload_lds16(Bsrc1, (char*)&lB[0][0] + wid * 2048 + 1024);
  __syncthreads();

  for (int k0 = 0; k0 < KS; k0 += 32) {
    int buf = (k0 >> 5) & 1;
    if (k0 + 32 < KS) {
      gload_lds16(Asrc0 + k0 + 32, (char*)&lA[buf ^ 1][0] + wid * 2048);
      gload_lds16(Asrc1 + k0 + 32, (char*)&lA[buf ^ 1][0] + wid * 2048 + 1024);
      gload_lds16(Bsrc0 + k0 + 32, (char*)&lB[buf ^ 1][0] + wid * 2048);
      gload_lds16(Bsrc1 + k0 + 32, (char*)&lB[buf ^ 1][0] + wid * 2048 + 1024);
    }
    const char* cA = (const char*)&lA[buf][0];
    const char* cB = (const char*)&lB[buf][0];
    bf16x8 af[4], bq[4];
#pragma unroll
    for (int m = 0; m < 4; m++) {
      int row = wr * 64 + m * 16 + l16;
      af[m] = *(const bf16x8*)(cA + row * 64 + ((g ^ (row & 3)) << 4));
    }
#pragma unroll
    for (int n = 0; n < 4; n++) {
      int row = wc * 64 + n * 16 + l16;
      bq[n] = *(const bf16x8*)(cB + row * 64 + ((g ^ (row & 3)) << 4));
    }
#pragma unroll
    for (int m = 0; m < 4; m++)
#pragma unroll
      for (int n = 0; n < 4; n++) acc[m][n] = mfma16(af[m], bq[n], acc[m][n]);
    __syncthreads();
  }

  int which = c0 / out_ncols;
  int cloc0 = c0 - which * out_ncols;
  size_t obase = (size_t)which * 8192 * out_ncols +
                 (size_t)split * 8192 * out_ncols * (NSPLIT > 1 ? 1 : 0);
  float osc = (EPI == 0 && which == 0) ? QSCALE : 1.0f;
#pragma unroll
  for (int n = 0; n < 4; n++) {
    int col = cloc0 + wc * 64 + n * 16 + l16;
    float bv = (EPI >= 1 && bias && split == 0) ? bias[col] : 0.f;
#pragma unroll
    for (int m = 0; m < 4; m++)
#pragma unroll
      for (int j = 0; j < 4; j++) {
        int row = rowbase + wr * 64 + m * 16 + g * 4 + j;
        float v = acc[m][n][j] + bv;
        size_t idx = obase + (size_t)row * out_ncols + col;
        if (EPI == 1) outb[idx] = (__bf16)fmaxf(v, 0.f);
        else if (EPI == 0) outb[idx] = (__bf16)(v * osc);
        else outf[idx] = v;
      }
  }
}

// ---------------- residual + LayerNorm: sums nsplit f32 partials ----------------
__global__ __launch_bounds__(256) void k_resln(const float* __restrict__ gin,
                                               int nsplit,
                                               const float* __restrict__ residf,
                                               const bf16_t* __restrict__ residb,
                                               const float* __restrict__ gam,
                                               const float* __restrict__ bet,
                                               float* __restrict__ outf,
                                               bf16_t* __restrict__ outb) {
  const size_t GS = (size_t)8192 * 512;
  int row = blockIdx.x * 4 + (threadIdx.x >> 6);
  int lane = threadIdx.x & 63;
  const float* gp = gin + (size_t)row * 512;
  float4 a0 = ((const float4*)gp)[lane];
  float4 a1 = ((const float4*)gp)[lane + 64];
  for (int s = 1; s < nsplit; s++) {
    const float* gp2 = gp + s * GS;
    float4 r0 = ((const float4*)gp2)[lane];
    float4 r1 = ((const float4*)gp2)[lane + 64];
    a0.x += r0.x; a0.y += r0.y; a0.z += r0.z; a0.w += r0.w;
    a1.x += r1.x; a1.y += r1.y; a1.z += r1.z; a1.w += r1.w;
  }
  if (residf) {
    const float* rp = residf + (size_t)row * 512;
    float4 r0 = ((const float4*)rp)[lane];
    float4 r1 = ((const float4*)rp)[lane + 64];
    a0.x += r0.x; a0.y += r0.y; a0.z += r0.z; a0.w += r0.w;
    a1.x += r1.x; a1.y += r1.y; a1.z += r1.z; a1.w += r1.w;
  } else {
    const bf16_t* rp = residb + (size_t)row * 512;
    bf16x4 r0 = ((const bf16x4*)rp)[lane];
    bf16x4 r1 = ((const bf16x4*)rp)[lane + 64];
    a0.x += (float)r0[0]; a0.y += (float)r0[1]; a0.z += (float)r0[2]; a0.w += (float)r0[3];
    a1.x += (float)r1[0]; a1.y += (float)r1[1]; a1.z += (float)r1[2]; a1.w += (float)r1[3];
  }
  float s = a0.x + a0.y + a0.z + a0.w + a1.x + a1.y + a1.z + a1.w;
  for (int off = 1; off < 64; off <<= 1) s += __shfl_xor(s, off);
  float mu = s * (1.f / 512.f);
  float sq = (a0.x - mu) * (a0.x - mu) + (a0.y - mu) * (a0.y - mu) +
             (a0.z - mu) * (a0.z - mu) + (a0.w - mu) * (a0.w - mu) +
             (a1.x - mu) * (a1.x - mu) + (a1.y - mu) * (a1.y - mu) +
             (a1.z - mu) * (a1.z - mu) + (a1.w - mu) * (a1.w - mu);
  for (int off = 1; off < 64; off <<= 1) sq += __shfl_xor(sq, off);
  float rs = rsqrtf(sq * (1.f / 512.f) + EPSC);

  float4 g0 = ((const float4*)gam)[lane], g1v = ((const float4*)gam)[lane + 64];
  float4 b0 = ((const float4*)bet)[lane], b1v = ((const float4*)bet)[lane + 64];
  float4 o0, o1;
  o0.x = (a0.x - mu) * rs * g0.x + b0.x;  o0.y = (a0.y - mu) * rs * g0.y + b0.y;
  o0.z = (a0.z - mu) * rs * g0.z + b0.z;  o0.w = (a0.w - mu) * rs * g0.w + b0.w;
  o1.x = (a1.x - mu) * rs * g1v.x + b1v.x; o1.y = (a1.y - mu) * rs * g1v.y + b1v.y;
  o1.z = (a1.z - mu) * rs * g1v.z + b1v.z; o1.w = (a1.w - mu) * rs * g1v.w + b1v.w;
  if (outf) {
    float* op = outf + (size_t)row * 512;
    ((float4*)op)[lane] = o0;
    ((float4*)op)[lane + 64] = o1;
  }
  if (outb) {
    bf16_t* op = outb + (size_t)row * 512;
    bf16x4 q0 = { (__bf16)o0.x, (__bf16)o0.y, (__bf16)o0.z, (__bf16)o0.w };
    bf16x4 q1 = { (__bf16)o1.x, (__bf16)o1.y, (__bf16)o1.z, (__bf16)o1.w };
    ((bf16x4*)op)[lane] = q0;
    ((bf16x4*)op)[lane + 64] = q1;
  }
}

// ---------------- v transpose (blk<1024, k-permuted) + kmax (blk>=1024) ----------------
__global__ __launch_bounds__(256) void k_vtrans_knorm(const bf16_t* __restrict__ v,
                                                      bf16_t* __restrict__ vT,
                                                      const bf16_t* __restrict__ kk,
                                                      float* __restrict__ kmax) {
  __shared__ bf16_t t[64 * 66];
  __shared__ float red[4];
  int bid = blockIdx.x;
  int tid = threadIdx.x, wid = tid >> 6, lane = tid & 63;
  if (bid < 1024) {
    int nt = bid & 15, h = (bid >> 4) & 7, b = bid >> 7;
    for (int i = 0; i < 16; i++) {
      int n = wid * 16 + i;
      t[lane * 66 + n] = v[(size_t)(b * 1024 + nt * 64 + n) * 512 + h * 64 + lane];
    }
    __syncthreads();
    int pi = (lane & 32) + (((lane >> 2) & 3) << 3) + (((lane >> 4) & 1) << 2) + (lane & 3);
    for (int i = 0; i < 16; i++) {
      int d = wid * 16 + i;
      vT[(size_t)((b * 8 + h) * 64 + d) * 1024 + nt * 64 + pi] = t[d * 66 + lane];
    }
  } else {
    int bh = bid - 1024;
    int b = bh >> 3, h = bh & 7;
    float mx = 0.f;
    for (int n = tid; n < 1024; n += 256) {
      const bf16_t* kp = kk + (size_t)(b * 1024 + n) * 512 + h * 64;
      float ss = 0.f;
#pragma unroll
      for (int vv = 0; vv < 8; vv++) {
        bf16x8 kv = *(const bf16x8*)(kp + vv * 8);
#pragma unroll
        for (int e = 0; e < 8; e++) { float f = (float)kv[e]; ss += f * f; }
      }
      mx = fmaxf(mx, ss);
    }
    for (int off = 1; off < 64; off <<= 1) mx = fmaxf(mx, __shfl_xor(mx, off));
    if (lane == 0) red[wid] = mx;
    __syncthreads();
    if (tid == 0) kmax[bh] = sqrtf(fmaxf(fmaxf(red[0], red[1]), fmaxf(red[2], red[3])));
  }
}

// ---------------- attention: ctx (normalized) + crl = C + log2(l) ----------------
// Swapped QK (s = mfma(K,Q)); register-P PV against pi-permuted V; row-sum l
// via mfma(pa, ones) -> lsacc in accumulator layout (no VALU ls adds, no
// cross-lane reduce). Counted barrier vmcnt(2)+s_barrier per tile.
__global__ __launch_bounds__(512) void k_attn_ctx(const bf16_t* __restrict__ q,
                                                  const bf16_t* __restrict__ kk,
                                                  const bf16_t* __restrict__ vT,
                                                  const bf16_t* __restrict__ eadjT,
                                                  const float* __restrict__ kmax,
                                                  bf16_t* __restrict__ ctx,
                                                  float* __restrict__ crl) {
  __shared__ bf16_t ldsK[2][4096];
  __shared__ bf16_t ldsV[2][4096];
  int bid = blockIdx.x;
  int qt = bid >> 6, h = bid & 7, b = (bid >> 3) & 7;
  int tid = threadIdx.x, wid = tid >> 6, lane = tid & 63;
  int l16 = lane & 15, g = lane >> 4;
  int qg0 = qt * 128 + wid * 16;
  int kvbase = (b * 8 + h) * 64;

  int d0 = wid * 1024 + lane * 16;
  int row0 = d0 >> 7;
  int cb0 = ((d0 >> 4) & 7) ^ (row0 & 7);
  const bf16_t* ksrc = kk + (size_t)(b * 1024) * 512 + h * 64;
  const bf16_t* vsrc = vT + (size_t)kvbase * 1024;

  auto stage = [&](int buf, int kc0) {
    gload_lds16(ksrc + (size_t)(kc0 + row0) * 512 + cb0 * 8, &ldsK[buf][wid * 512]);
    gload_lds16(vsrc + (size_t)row0 * 1024 + kc0 + cb0 * 8, &ldsV[buf][wid * 512]);
  };

  const bf16_t* qp = q + (size_t)(b * 1024 + qg0 + l16) * 512 + h * 64 + 8 * g;
  bf16x8 aq0 = *(const bf16x8*)qp;
  bf16x8 aq1 = *(const bf16x8*)(qp + 32);

  // C = |q'| * kmax (per lane: own q-row l16); Cj[j] = bound for row g*4+j
  float kmaxv = kmax[b * 8 + h];
  float ssq = 0.f;
#pragma unroll
  for (int e = 0; e < 8; e++) {
    float f0 = (float)aq0[e], f1 = (float)aq1[e];
    ssq += f0 * f0 + f1 * f1;
  }
  ssq += __shfl_xor(ssq, 16);
  ssq += __shfl_xor(ssq, 32);
  float Cn = sqrtf(ssq) * kmaxv;
  f32x4 negC4 = (f32x4){-Cn, -Cn, -Cn, -Cn};
  float Cj[4];
#pragma unroll
  for (int j = 0; j < 4; j++) Cj[j] = __shfl(Cn, g * 4 + j);

  bf16x8 ones;
#pragma unroll
  for (int e = 0; e < 8; e++) ones[e] = (__bf16)1.0f;

  f32x4 cacc[4];
#pragma unroll
  for (int d = 0; d < 4; d++) cacc[d] = (f32x4){0.f, 0.f, 0.f, 0.f};
  f32x4 lsacc = (f32x4){0.f, 0.f, 0.f, 0.f};
  int rph = l16 & 7;
  const bf16_t* erowT = eadjT + (size_t)(qg0 + l16) * 1024 + g * 16;

  bf16x8 eaA[2], eaB[2];
  auto loadEA = [&](bf16x8 (&d)[2], int kc0) {
    d[0] = *(const bf16x8*)(erowT + kc0);
    d[1] = *(const bf16x8*)(erowT + kc0 + 8);
  };

  auto cbar = [&]() {
    __builtin_amdgcn_sched_barrier(0);
    asm volatile("s_waitcnt vmcnt(2) lgkmcnt(0)" ::: "memory");
    __builtin_amdgcn_sched_barrier(0);
    __builtin_amdgcn_s_barrier();
    __builtin_amdgcn_sched_barrier(0);
  };

  auto tile = [&](int kt, int buf, bf16x8 (&eaC)[2], bf16x8 (&eaN)[2]) {
    int ktn = (kt + 1 < 16) ? kt + 1 : 15;
    stage(buf ^ 1, ktn * 64);
    loadEA(eaN, ktn * 64);

    const char* curK = (const char*)ldsK[buf];
    const char* curV = (const char*)ldsV[buf];

    bf16x8 pa0, pa1;
#pragma unroll
    for (int cg = 0; cg < 4; cg++) {
      const char* krow = curK + ((cg * 16 + l16) << 7);
      bf16x8 k0 = *(const bf16x8*)(krow + ((g ^ rph) << 4));
      bf16x8 k1 = *(const bf16x8*)(krow + (((g + 4) ^ rph) << 4));
      __builtin_amdgcn_s_setprio(1);
      f32x4 s = mfma16(k0, aq0, negC4);     // SWAPPED: A=K, B=Q -> col=q=l16
      s = mfma16(k1, aq1, s);
      __builtin_amdgcn_s_setprio(0);
#pragma unroll
      for (int j = 0; j < 4; j++) {
        float p = (float)eaC[cg >> 1][(cg & 1) * 4 + j] * exp2f(s[j]);
        if (cg < 2) pa0[cg * 4 + j] = (__bf16)p;
        else        pa1[(cg - 2) * 4 + j] = (__bf16)p;
      }
    }
#pragma unroll
    for (int half = 0; half < 2; half++) {
      bf16x8 pa = half ? pa1 : pa0;
      __builtin_amdgcn_s_setprio(1);
#pragma unroll
      for (int dg = 0; dg < 4; dg++) {
        const char* vrow = curV + ((dg * 16 + l16) << 7);
        bf16x8 vv = *(const bf16x8*)(vrow + (((g + half * 4) ^ rph) << 4));
        cacc[dg] = mfma16(pa, vv, cacc[dg]);
      }
      lsacc = mfma16(pa, ones, lsacc);      // row-sum l on the matrix pipe
      __builtin_amdgcn_s_setprio(0);
    }
    cbar();
  };

  // prologue
  stage(0, 0);
  loadEA(eaA, 0);
  cbar();

  for (int k2 = 0; k2 < 8; k2++) {
    tile(2 * k2,     0, eaA, eaB);
    tile(2 * k2 + 1, 1, eaB, eaA);
  }

  // lsacc[j] = full row sum for q = g*4+j (replicated across l16 columns)
  float rcj[4];
#pragma unroll
  for (int j = 0; j < 4; j++) rcj[j] = (lsacc[j] > 0.f) ? (1.f / lsacc[j]) : 0.f;

#pragma unroll
  for (int dg = 0; dg < 4; dg++)
#pragma unroll
    for (int j = 0; j < 4; j++) {
      int row = qg0 + g * 4 + j;
      ctx[(size_t)(b * 1024 + row) * 512 + h * 64 + dg * 16 + l16] =
          (__bf16)(cacc[dg][j] * rcj[j]);
    }
  if (l16 == 0) {
#pragma unroll
    for (int j = 0; j < 4; j++) {
      int li = (b * 8 + h) * 1024 + qg0 + g * 4 + j;
      crl[li] = (lsacc[j] > 0.f) ? (Cj[j] + __log2f(lsacc[j])) : 1.0e30f;
    }
  }
}

// ---------------- attention mean over heads -> mout (barrier-free, swapped QK) ----------------
__global__ __launch_bounds__(256, 4) void k_attn_mean(const bf16_t* __restrict__ q,
                                                      const bf16_t* __restrict__ kk,
                                                      const bf16_t* __restrict__ eadjT,
                                                      const float* __restrict__ crl,
                                                      float* __restrict__ mout) {
  __shared__ bf16_t lds[4][2][2048];   // [wave][buf][4KB]
  int bid = blockIdx.x;
  int kq = bid & 7, qt = (bid >> 3) & 15, b = bid >> 7;
  int tid = threadIdx.x, wid = tid >> 6, lane = tid & 63;
  int l16 = lane & 15, g = lane >> 4;
  int qg0 = qt * 64 + wid * 16;
  int kbase = kq * 128;
  int rl = lane >> 3;
  int cb = (lane & 7) ^ rl;
  const bf16_t* ksrc = kk + (size_t)(b * 1024 + kbase) * 512;

  auto stage = [&](int t) {
    int h = t >> 2, c = t & 3;
    char* dst = (char*)&lds[wid][t & 1][0];
    const bf16_t* sp = ksrc + (size_t)(c * 32 + rl) * 512 + h * 64 + cb * 8;
#pragma unroll
    for (int i = 0; i < 4; i++)
      gload_lds16(sp + (size_t)i * 8 * 512, dst + i * 1024);
  };

  f32x4 macc[8];
#pragma unroll
  for (int kg = 0; kg < 8; kg++) macc[kg] = (f32x4){0.f, 0.f, 0.f, 0.f};

  stage(0);

  for (int h = 0; h < 8; h++) {
    const bf16_t* qp = q + (size_t)(b * 1024 + qg0 + l16) * 512 + h * 64 + 8 * g;
    bf16x8 aq0 = *(const bf16x8*)qp;
    bf16x8 aq1 = *(const bf16x8*)(qp + 32);
    float CRs = crl[(b * 8 + h) * 1024 + qg0 + l16];   // own q-row
    f32x4 negCR4 = (f32x4){-CRs, -CRs, -CRs, -CRs};
#pragma unroll
    for (int c = 0; c < 4; c++) {
      int t = h * 4 + c;
      __builtin_amdgcn_sched_barrier(0);
      if (t < 31) {
        stage(t + 1);
        __builtin_amdgcn_sched_barrier(0);
        asm volatile("s_waitcnt vmcnt(4)" ::: "memory");
      } else {
        asm volatile("s_waitcnt vmcnt(0)" ::: "memory");
      }
      __builtin_amdgcn_sched_barrier(0);
      const char* cK = (const char*)&lds[wid][t & 1][0];
#pragma unroll
      for (int cg = 0; cg < 2; cg++) {
        const char* krow = cK + ((cg * 16 + l16) << 7);
        bf16x8 k0 = *(const bf16x8*)(krow + ((g ^ (l16 & 7)) << 4));
        bf16x8 k1 = *(const bf16x8*)(krow + (((g + 4) ^ (l16 & 7)) << 4));
        __builtin_amdgcn_s_setprio(1);
        f32x4 s = mfma16(k0, aq0, negCR4);   // SWAPPED
        s = mfma16(k1, aq1, s);
        __builtin_amdgcn_s_setprio(0);
        int kg = c * 2 + cg;
#pragma unroll
        for (int j = 0; j < 4; j++)
          macc[kg][j] += exp2f(s[j]);
      }
    }
  }

  // epilogue: k = kbase + kg*16 + g*4 + j for q = l16.
  const bf16_t* erowT = eadjT + (size_t)(qg0 + l16) * 1024 + kbase + g * 16;
  bf16x8 eA0 = *(const bf16x8*)(erowT);        // group A, c' 0,1
  bf16x8 eA1 = *(const bf16x8*)(erowT + 8);    // group A, c' 2,3
  bf16x8 eB0 = *(const bf16x8*)(erowT + 64);   // group B, c' 0,1
  bf16x8 eB1 = *(const bf16x8*)(erowT + 72);   // group B, c' 2,3
  float* mrow = mout + (size_t)b * 1048576 + (size_t)(qg0 + l16) * 1024 + kbase;
#pragma unroll
  for (int kg = 0; kg < 8; kg++) {
    bf16x8 eg = (kg < 2) ? eA0 : (kg < 4) ? eA1 : (kg < 6) ? eB0 : eB1;
    f32x4 mv;
#pragma unroll
    for (int j = 0; j < 4; j++)
      mv[j] = macc[kg][j] * (float)eg[(kg & 1) * 4 + j] * 0.125f;
    *(f32x4*)(mrow + kg * 16 + g * 4) = mv;
  }
}

extern "C" void kernel_launch(void* const* d_in, const int* in_sizes, int n_in,
                              void* d_out, int out_size, void* d_ws, size_t ws_size,
                              hipStream_t stream) {
  (void)in_sizes; (void)n_in; (void)out_size; (void)ws_size;
  const float* x   = (const float*)d_in[0];
  const float* adj = (const float*)d_in[1];
  const int*   msk = (const int*)d_in[2];
  const float* Wq  = (const float*)d_in[3];
  const float* Wk  = (const float*)d_in[4];
  const float* Wv  = (const float*)d_in[5];
  const float* Wo  = (const float*)d_in[6];
  const float* W1  = (const float*)d_in[7];
  const float* b1  = (const float*)d_in[8];
  const float* W2  = (const float*)d_in[9];
  const float* b2  = (const float*)d_in[10];
  const float* g1  = (const float*)d_in[11];
  const float* be1 = (const float*)d_in[12];
  const float* g2  = (const float*)d_in[13];
  const float* be2 = (const float*)d_in[14];

  float* out  = (float*)d_out;
  float* mout = out + (size_t)8 * 1024 * 512;

  char* ws = (char*)d_ws;
  const size_t MB = 1024 * 1024;
  bf16_t* wqb = (bf16_t*)(ws);
  bf16_t* wkb = (bf16_t*)(ws + 512 * 1024);
  bf16_t* wvb = (bf16_t*)(ws + 1 * MB);
  bf16_t* wob = (bf16_t*)(ws + 3 * MB / 2);
  bf16_t* w1b = (bf16_t*)(ws + 2 * MB);
  bf16_t* w2b = (bf16_t*)(ws + 4 * MB);
  float*  crl  = (float*)(ws + 6 * MB + 256 * 1024); // 256 KB (C + log2 l)
  float*  kmax = (float*)(ws + 6 * MB + 768 * 1024); // 256 B
  bf16_t* xb   = (bf16_t*)(ws + 8 * MB);   // 8-16: x bf16; then ctx; then zb
  bf16_t* ctx  = xb;
  bf16_t* zb   = xb;
  bf16_t* qb   = (bf16_t*)(ws + 16 * MB);  // 16-24 (dead after attn_mean)
  bf16_t* kb   = (bf16_t*)(ws + 24 * MB);  // 24-32 (dead after attn_mean)
  bf16_t* vb   = (bf16_t*)(ws + 32 * MB);  // 32-40 (dead after vtrans)
  bf16_t* vT   = (bf16_t*)(ws + 40 * MB);  // 40-48 (dead after attn_ctx)
  float*  gout1 = (float*)(ws + 16 * MB);  // 16-48: 2x16MB f32 (wo split-K partials)
  bf16_t* hb    = (bf16_t*)(ws + 16 * MB); // 16-48 bf16 (ffn1 -> ffn2)
  float*  gout2 = (float*)(ws + 44 * MB);  // 44-76: 2x16MB f32 (ffn2 split-K partials)
  bf16_t* eadjT = (bf16_t*)(ws + 72 * MB); // 72-74 permuted exp(adj)*mask table
  // eadjT (72-74) overlaps gout2 split1 (60-76): eadjT is dead after attn_mean,
  // which completes before the ffn2 gemm writes gout2. Safe.

  // converts + eadj prep (one launch)
  k_cvtall<<<7424, 256, 0, stream>>>(x, Wq, Wk, Wv, Wo, W1, W2, adj, msk,
                                     xb, wqb, wkb, wvb, wob, w1b, w2b, eadjT);

  // QKV: one GEMM, N=1536 (wq|wk|wv contiguous); q pre-scaled by 0.125*log2e
  k_gemm<0, 1><<<64 * 12, 256, 0, stream>>>(xb, wqb, 512, 12, nullptr, qb, nullptr, 512);
  // v transpose (k-permuted) + kmax in one launch
  k_vtrans_knorm<<<1088, 256, 0, stream>>>(vb, vT, kb, kmax);

  // attention: ctx (swapped-QK register-P pipeline, MFMA row-sum) + crl, then mean
  k_attn_ctx<<<512, 512, 0, stream>>>(qb, kb, vT, eadjT, kmax, ctx, crl);
  k_attn_mean<<<1024, 256, 0, stream>>>(qb, kb, eadjT, crl, mout);

  // Wo proj (split-K x2) -> gout1[2]; residual(x f32) + LN1 -> zb (bf16)
  k_gemm<2, 2><<<2 * 64 * 4, 256, 0, stream>>>(ctx, wob, 512, 4, nullptr, nullptr, gout1, 512);
  k_resln<<<2048, 256, 0, stream>>>(gout1, 2, x, nullptr, g1, be1, nullptr, zb);
  // FFN1: relu(zb @ W1^T + b1) -> hb
  k_gemm<1, 1><<<64 * 16, 256, 0, stream>>>(zb, w1b, 512, 16, b1, hb, nullptr, 2048);
  // FFN2 (split-K x2) -> gout2[2]; residual(zb bf16) + LN2 -> out
  k_gemm<2, 2><<<2 * 64 * 4, 256, 0, stream>>>(hb, w2b, 2048, 4, b2, nullptr, gout2, 512);
  k_resln<<<2048, 256, 0, stream>>>(gout2, 2, nullptr, zb, g2, be2, out, nullptr);
}

// Round 16
// 212.316 us; speedup vs baseline: 1.1331x; 1.0271x over previous
//
#include <hip/hip_runtime.h>
#include <math.h>
#include <stdint.h>

// GraphTransformerLayer on MI355X (gfx950).
// B=8, N=1024, D=512, H=8, Dh=64, F=2048.
// Round 16: split-K partials in bf16 (EPI=2 writes bf16; k_resln reads bf16
//           partials with one bf16x8 load/lane) -> -64MB HBM round-trip.
//           Rest identical to round 15.

using bf16_t = __bf16;
typedef __attribute__((__ext_vector_type__(8))) __bf16 bf16x8;
typedef __attribute__((__ext_vector_type__(4))) __bf16 bf16x4;
typedef __attribute__((__ext_vector_type__(4))) float  f32x4;

#define DEVI __device__ __forceinline__

DEVI f32x4 mfma16(bf16x8 a, bf16x8 b, f32x4 c) {
  return __builtin_amdgcn_mfma_f32_16x16x32_bf16(a, b, c, 0, 0, 0);
}

// async global->LDS, 16B per lane. dest = wave-uniform base (+ lane*16 by HW).
DEVI void gload_lds16(const void* g, void* l) {
  __builtin_amdgcn_global_load_lds(
      (const __attribute__((address_space(1))) uint32_t*)g,
      (__attribute__((address_space(3))) uint32_t*)l, 16, 0, 0);
}

#define EPSC  (1e-5f)
#define QSCALE 0.18033688f   // 0.125 * log2(e): scores come out of MFMA in base-2

// ---------------- fused converts: x (4096) + weights (3072) + eadj prep (256) ----------------
// eadj stored PERMUTED within each 64-col group: pos = g*16 + c*4 + j where
// k = c*16 + g*4 + j (g=(k>>2)&3, c=(k>>4)&3, j=k&3).
__global__ __launch_bounds__(256) void k_cvtall(const float* __restrict__ x,
                                                const float* __restrict__ wq,
                                                const float* __restrict__ wk,
                                                const float* __restrict__ wv,
                                                const float* __restrict__ wo,
                                                const float* __restrict__ w1,
                                                const float* __restrict__ w2,
                                                const float* __restrict__ adj,
                                                const int* __restrict__ msk,
                                                bf16_t* __restrict__ ox,
                                                bf16_t* __restrict__ owq,
                                                bf16_t* __restrict__ owk,
                                                bf16_t* __restrict__ owv,
                                                bf16_t* __restrict__ owo,
                                                bf16_t* __restrict__ ow1,
                                                bf16_t* __restrict__ ow2,
                                                bf16_t* __restrict__ eadjT) {
  int blk = blockIdx.x;
  if (blk >= 7168) {  // eadj prep: 256 blocks x 4 rows
    int row  = (blk - 7168) * 4 + (threadIdx.x >> 6);
    int lane = threadIdx.x & 63;
    for (int i = 0; i < 16; i++) {
      int c = lane + 64 * i;
      size_t idx = (size_t)row * 1024 + c;
      float a = adj[idx];
      bool valid = (msk[idx] != 0);
      int pos = (c & ~63) + (((c >> 2) & 3) << 4) + (((c >> 4) & 3) << 2) + (c & 3);
      eadjT[(size_t)row * 1024 + pos] = valid ? (__bf16)__expf(a) : (__bf16)0.f;
    }
    return;
  }
  const float* src; bf16_t* dst; int base;
  if (blk < 4096)      { src = x;  dst = ox;  base = blk; }
  else {
    blk -= 4096;
    if      (blk < 256)  { src = wq; dst = owq; base = blk; }
    else if (blk < 512)  { src = wk; dst = owk; base = blk - 256; }
    else if (blk < 768)  { src = wv; dst = owv; base = blk - 512; }
    else if (blk < 1024) { src = wo; dst = owo; base = blk - 768; }
    else if (blk < 2048) { src = w1; dst = ow1; base = blk - 1024; }
    else                 { src = w2; dst = ow2; base = blk - 2048; }
  }
  int i = base * 256 + threadIdx.x;
  float4 v = ((const float4*)src)[i];
  bf16x4 o = { (__bf16)v.x, (__bf16)v.y, (__bf16)v.z, (__bf16)v.w };
  ((bf16x4*)dst)[i] = o;
}

// ---------------- tiled GEMM: C[8192 x N] = A[8192 x K] @ B[N x K]^T ----------------
// EPI: 0 = bf16 store with which-routing (+QSCALE for q), 1 = bf16 bias+relu,
//      2 = bf16 partial (+bias at split 0).
template<int EPI, int NSPLIT>
__global__ __launch_bounds__(256) void k_gemm(const bf16_t* __restrict__ A,
                                              const bf16_t* __restrict__ B,
                                              int K, int nbx,
                                              const float* __restrict__ bias,
                                              bf16_t* __restrict__ outb,
                                              int out_ncols) {
  __shared__ bf16_t lA[2][4096];
  __shared__ bf16_t lB[2][4096];
  int bid = blockIdx.x;
  int bps = 64 * nbx;
  int split = bid / bps, r = bid - split * bps;
  int nb = r % nbx, mb = r / nbx;
  int KS = K / NSPLIT;
  const bf16_t* Ab = A + (size_t)split * KS;
  const bf16_t* Bb = B + (size_t)split * KS;
  int tid = threadIdx.x, wid = tid >> 6, lane = tid & 63;
  int l16 = lane & 15, g = lane >> 4;
  int wr = wid >> 1, wc = wid & 1;
  int rowbase = mb * 128, c0 = nb * 128;

  int dA0 = wid * 2048 + lane * 16;
  int rA0 = dA0 >> 6;
  int cbA = ((dA0 >> 4) & 3) ^ (rA0 & 3);
  const bf16_t* Asrc0 = Ab + (size_t)(rowbase + rA0) * K + cbA * 8;
  const bf16_t* Asrc1 = Ab + (size_t)(rowbase + rA0 + 16) * K + cbA * 8;
  const bf16_t* Bsrc0 = Bb + (size_t)(c0 + rA0) * K + cbA * 8;
  const bf16_t* Bsrc1 = Bb + (size_t)(c0 + rA0 + 16) * K + cbA * 8;

  f32x4 acc[4][4];
#pragma unroll
  for (int m = 0; m < 4; m++)
#pragma unroll
    for (int n = 0; n < 4; n++) acc[m][n] = (f32x4){0.f, 0.f, 0.f, 0.f};

  gload_lds16(Asrc0, (char*)&lA[0][0] + wid * 2048);
  gload_lds16(Asrc1, (char*)&lA[0][0] + wid * 2048 + 1024);
  gload_lds16(Bsrc0, (char*)&lB[0][0] + wid * 2048);
  gload_lds16(Bsrc1, (char*)&lB[0][0] + wid * 2048 + 1024);
  __syncthreads();

  for (int k0 = 0; k0 < KS; k0 += 32) {
    int buf = (k0 >> 5) & 1;
    if (k0 + 32 < KS) {
      gload_lds16(Asrc0 + k0 + 32, (char*)&lA[buf ^ 1][0] + wid * 2048);
      gload_lds16(Asrc1 + k0 + 32, (char*)&lA[buf ^ 1][0] + wid * 2048 + 1024);
      gload_lds16(Bsrc0 + k0 + 32, (char*)&lB[buf ^ 1][0] + wid * 2048);
      gload_lds16(Bsrc1 + k0 + 32, (char*)&lB[buf ^ 1][0] + wid * 2048 + 1024);
    }
    const char* cA = (const char*)&lA[buf][0];
    const char* cB = (const char*)&lB[buf][0];
    bf16x8 af[4], bq[4];
#pragma unroll
    for (int m = 0; m < 4; m++) {
      int row = wr * 64 + m * 16 + l16;
      af[m] = *(const bf16x8*)(cA + row * 64 + ((g ^ (row & 3)) << 4));
    }
#pragma unroll
    for (int n = 0; n < 4; n++) {
      int row = wc * 64 + n * 16 + l16;
      bq[n] = *(const bf16x8*)(cB + row * 64 + ((g ^ (row & 3)) << 4));
    }
#pragma unroll
    for (int m = 0; m < 4; m++)
#pragma unroll
      for (int n = 0; n < 4; n++) acc[m][n] = mfma16(af[m], bq[n], acc[m][n]);
    __syncthreads();
  }

  int which = c0 / out_ncols;
  int cloc0 = c0 - which * out_ncols;
  size_t obase = (size_t)which * 8192 * out_ncols +
                 (size_t)split * 8192 * out_ncols * (NSPLIT > 1 ? 1 : 0);
  float osc = (EPI == 0 && which == 0) ? QSCALE : 1.0f;
#pragma unroll
  for (int n = 0; n < 4; n++) {
    int col = cloc0 + wc * 64 + n * 16 + l16;
    float bv = (EPI >= 1 && bias && split == 0) ? bias[col] : 0.f;
#pragma unroll
    for (int m = 0; m < 4; m++)
#pragma unroll
      for (int j = 0; j < 4; j++) {
        int row = rowbase + wr * 64 + m * 16 + g * 4 + j;
        float v = acc[m][n][j] + bv;
        size_t idx = obase + (size_t)row * out_ncols + col;
        if (EPI == 1) outb[idx] = (__bf16)fmaxf(v, 0.f);
        else if (EPI == 0) outb[idx] = (__bf16)(v * osc);
        else outb[idx] = (__bf16)v;            // bf16 partial
      }
  }
}

// ---------------- residual + LayerNorm: sums nsplit bf16 partials ----------------
// lane holds elems 8*lane .. 8*lane+7 of its row (one bf16x8 load per partial).
__global__ __launch_bounds__(256) void k_resln(const bf16_t* __restrict__ gin,
                                               int nsplit,
                                               const float* __restrict__ residf,
                                               const bf16_t* __restrict__ residb,
                                               const float* __restrict__ gam,
                                               const float* __restrict__ bet,
                                               float* __restrict__ outf,
                                               bf16_t* __restrict__ outb) {
  const size_t GS = (size_t)8192 * 512;
  int row = blockIdx.x * 4 + (threadIdx.x >> 6);
  int lane = threadIdx.x & 63;
  const bf16_t* gp = gin + (size_t)row * 512;
  float a[8];
  {
    bf16x8 v = ((const bf16x8*)gp)[lane];
#pragma unroll
    for (int e = 0; e < 8; e++) a[e] = (float)v[e];
  }
  for (int s = 1; s < nsplit; s++) {
    bf16x8 v = ((const bf16x8*)(gp + s * GS))[lane];
#pragma unroll
    for (int e = 0; e < 8; e++) a[e] += (float)v[e];
  }
  if (residf) {
    const float* rp = residf + (size_t)row * 512;
    float4 r0 = ((const float4*)rp)[2 * lane];
    float4 r1 = ((const float4*)rp)[2 * lane + 1];
    a[0] += r0.x; a[1] += r0.y; a[2] += r0.z; a[3] += r0.w;
    a[4] += r1.x; a[5] += r1.y; a[6] += r1.z; a[7] += r1.w;
  } else {
    bf16x8 r = ((const bf16x8*)(residb + (size_t)row * 512))[lane];
#pragma unroll
    for (int e = 0; e < 8; e++) a[e] += (float)r[e];
  }
  float s = 0.f;
#pragma unroll
  for (int e = 0; e < 8; e++) s += a[e];
  for (int off = 1; off < 64; off <<= 1) s += __shfl_xor(s, off);
  float mu = s * (1.f / 512.f);
  float sq = 0.f;
#pragma unroll
  for (int e = 0; e < 8; e++) { float d = a[e] - mu; sq += d * d; }
  for (int off = 1; off < 64; off <<= 1) sq += __shfl_xor(sq, off);
  float rs = rsqrtf(sq * (1.f / 512.f) + EPSC);

  float4 g0 = ((const float4*)gam)[2 * lane], g1v = ((const float4*)gam)[2 * lane + 1];
  float4 b0 = ((const float4*)bet)[2 * lane], b1v = ((const float4*)bet)[2 * lane + 1];
  float o[8];
  o[0] = (a[0] - mu) * rs * g0.x + b0.x;  o[1] = (a[1] - mu) * rs * g0.y + b0.y;
  o[2] = (a[2] - mu) * rs * g0.z + b0.z;  o[3] = (a[3] - mu) * rs * g0.w + b0.w;
  o[4] = (a[4] - mu) * rs * g1v.x + b1v.x; o[5] = (a[5] - mu) * rs * g1v.y + b1v.y;
  o[6] = (a[6] - mu) * rs * g1v.z + b1v.z; o[7] = (a[7] - mu) * rs * g1v.w + b1v.w;
  if (outf) {
    float* op = outf + (size_t)row * 512;
    ((float4*)op)[2 * lane]     = (float4){o[0], o[1], o[2], o[3]};
    ((float4*)op)[2 * lane + 1] = (float4){o[4], o[5], o[6], o[7]};
  }
  if (outb) {
    bf16x8 q;
#pragma unroll
    for (int e = 0; e < 8; e++) q[e] = (__bf16)o[e];
    ((bf16x8*)(outb + (size_t)row * 512))[lane] = q;
  }
}

// ---------------- v transpose (blk<1024, k-permuted) + kmax (blk>=1024) ----------------
__global__ __launch_bounds__(256) void k_vtrans_knorm(const bf16_t* __restrict__ v,
                                                      bf16_t* __restrict__ vT,
                                                      const bf16_t* __restrict__ kk,
                                                      float* __restrict__ kmax) {
  __shared__ bf16_t t[64 * 66];
  __shared__ float red[4];
  int bid = blockIdx.x;
  int tid = threadIdx.x, wid = tid >> 6, lane = tid & 63;
  if (bid < 1024) {
    int nt = bid & 15, h = (bid >> 4) & 7, b = bid >> 7;
    for (int i = 0; i < 16; i++) {
      int n = wid * 16 + i;
      t[lane * 66 + n] = v[(size_t)(b * 1024 + nt * 64 + n) * 512 + h * 64 + lane];
    }
    __syncthreads();
    int pi = (lane & 32) + (((lane >> 2) & 3) << 3) + (((lane >> 4) & 1) << 2) + (lane & 3);
    for (int i = 0; i < 16; i++) {
      int d = wid * 16 + i;
      vT[(size_t)((b * 8 + h) * 64 + d) * 1024 + nt * 64 + pi] = t[d * 66 + lane];
    }
  } else {
    int bh = bid - 1024;
    int b = bh >> 3, h = bh & 7;
    float mx = 0.f;
    for (int n = tid; n < 1024; n += 256) {
      const bf16_t* kp = kk + (size_t)(b * 1024 + n) * 512 + h * 64;
      float ss = 0.f;
#pragma unroll
      for (int vv = 0; vv < 8; vv++) {
        bf16x8 kv = *(const bf16x8*)(kp + vv * 8);
#pragma unroll
        for (int e = 0; e < 8; e++) { float f = (float)kv[e]; ss += f * f; }
      }
      mx = fmaxf(mx, ss);
    }
    for (int off = 1; off < 64; off <<= 1) mx = fmaxf(mx, __shfl_xor(mx, off));
    if (lane == 0) red[wid] = mx;
    __syncthreads();
    if (tid == 0) kmax[bh] = sqrtf(fmaxf(fmaxf(red[0], red[1]), fmaxf(red[2], red[3])));
  }
}

// ---------------- attention: ctx (normalized) + crl = C + log2(l) ----------------
// Swapped QK (s = mfma(K,Q)); register-P PV against pi-permuted V; row-sum l
// via mfma(pa, ones). Counted barrier vmcnt(2)+s_barrier per tile.
__global__ __launch_bounds__(512) void k_attn_ctx(const bf16_t* __restrict__ q,
                                                  const bf16_t* __restrict__ kk,
                                                  const bf16_t* __restrict__ vT,
                                                  const bf16_t* __restrict__ eadjT,
                                                  const float* __restrict__ kmax,
                                                  bf16_t* __restrict__ ctx,
                                                  float* __restrict__ crl) {
  __shared__ bf16_t ldsK[2][4096];
  __shared__ bf16_t ldsV[2][4096];
  int bid = blockIdx.x;
  int qt = bid >> 6, h = bid & 7, b = (bid >> 3) & 7;
  int tid = threadIdx.x, wid = tid >> 6, lane = tid & 63;
  int l16 = lane & 15, g = lane >> 4;
  int qg0 = qt * 128 + wid * 16;
  int kvbase = (b * 8 + h) * 64;

  int d0 = wid * 1024 + lane * 16;
  int row0 = d0 >> 7;
  int cb0 = ((d0 >> 4) & 7) ^ (row0 & 7);
  const bf16_t* ksrc = kk + (size_t)(b * 1024) * 512 + h * 64;
  const bf16_t* vsrc = vT + (size_t)kvbase * 1024;

  auto stage = [&](int buf, int kc0) {
    gload_lds16(ksrc + (size_t)(kc0 + row0) * 512 + cb0 * 8, &ldsK[buf][wid * 512]);
    gload_lds16(vsrc + (size_t)row0 * 1024 + kc0 + cb0 * 8, &ldsV[buf][wid * 512]);
  };

  const bf16_t* qp = q + (size_t)(b * 1024 + qg0 + l16) * 512 + h * 64 + 8 * g;
  bf16x8 aq0 = *(const bf16x8*)qp;
  bf16x8 aq1 = *(const bf16x8*)(qp + 32);

  float kmaxv = kmax[b * 8 + h];
  float ssq = 0.f;
#pragma unroll
  for (int e = 0; e < 8; e++) {
    float f0 = (float)aq0[e], f1 = (float)aq1[e];
    ssq += f0 * f0 + f1 * f1;
  }
  ssq += __shfl_xor(ssq, 16);
  ssq += __shfl_xor(ssq, 32);
  float Cn = sqrtf(ssq) * kmaxv;
  f32x4 negC4 = (f32x4){-Cn, -Cn, -Cn, -Cn};
  float Cj[4];
#pragma unroll
  for (int j = 0; j < 4; j++) Cj[j] = __shfl(Cn, g * 4 + j);

  bf16x8 ones;
#pragma unroll
  for (int e = 0; e < 8; e++) ones[e] = (__bf16)1.0f;

  f32x4 cacc[4];
#pragma unroll
  for (int d = 0; d < 4; d++) cacc[d] = (f32x4){0.f, 0.f, 0.f, 0.f};
  f32x4 lsacc = (f32x4){0.f, 0.f, 0.f, 0.f};
  int rph = l16 & 7;
  const bf16_t* erowT = eadjT + (size_t)(qg0 + l16) * 1024 + g * 16;

  bf16x8 eaA[2], eaB[2];
  auto loadEA = [&](bf16x8 (&d)[2], int kc0) {
    d[0] = *(const bf16x8*)(erowT + kc0);
    d[1] = *(const bf16x8*)(erowT + kc0 + 8);
  };

  auto cbar = [&]() {
    __builtin_amdgcn_sched_barrier(0);
    asm volatile("s_waitcnt vmcnt(2) lgkmcnt(0)" ::: "memory");
    __builtin_amdgcn_sched_barrier(0);
    __builtin_amdgcn_s_barrier();
    __builtin_amdgcn_sched_barrier(0);
  };

  auto tile = [&](int kt, int buf, bf16x8 (&eaC)[2], bf16x8 (&eaN)[2]) {
    int ktn = (kt + 1 < 16) ? kt + 1 : 15;
    stage(buf ^ 1, ktn * 64);
    loadEA(eaN, ktn * 64);

    const char* curK = (const char*)ldsK[buf];
    const char* curV = (const char*)ldsV[buf];

    bf16x8 pa0, pa1;
#pragma unroll
    for (int cg = 0; cg < 4; cg++) {
      const char* krow = curK + ((cg * 16 + l16) << 7);
      bf16x8 k0 = *(const bf16x8*)(krow + ((g ^ rph) << 4));
      bf16x8 k1 = *(const bf16x8*)(krow + (((g + 4) ^ rph) << 4));
      __builtin_amdgcn_s_setprio(1);
      f32x4 s = mfma16(k0, aq0, negC4);     // SWAPPED: A=K, B=Q -> col=q=l16
      s = mfma16(k1, aq1, s);
      __builtin_amdgcn_s_setprio(0);
#pragma unroll
      for (int j = 0; j < 4; j++) {
        float p = (float)eaC[cg >> 1][(cg & 1) * 4 + j] * exp2f(s[j]);
        if (cg < 2) pa0[cg * 4 + j] = (__bf16)p;
        else        pa1[(cg - 2) * 4 + j] = (__bf16)p;
      }
    }
#pragma unroll
    for (int half = 0; half < 2; half++) {
      bf16x8 pa = half ? pa1 : pa0;
      __builtin_amdgcn_s_setprio(1);
#pragma unroll
      for (int dg = 0; dg < 4; dg++) {
        const char* vrow = curV + ((dg * 16 + l16) << 7);
        bf16x8 vv = *(const bf16x8*)(vrow + (((g + half * 4) ^ rph) << 4));
        cacc[dg] = mfma16(pa, vv, cacc[dg]);
      }
      lsacc = mfma16(pa, ones, lsacc);      // row-sum l on the matrix pipe
      __builtin_amdgcn_s_setprio(0);
    }
    cbar();
  };

  stage(0, 0);
  loadEA(eaA, 0);
  cbar();

  for (int k2 = 0; k2 < 8; k2++) {
    tile(2 * k2,     0, eaA, eaB);
    tile(2 * k2 + 1, 1, eaB, eaA);
  }

  float rcj[4];
#pragma unroll
  for (int j = 0; j < 4; j++) rcj[j] = (lsacc[j] > 0.f) ? (1.f / lsacc[j]) : 0.f;

#pragma unroll
  for (int dg = 0; dg < 4; dg++)
#pragma unroll
    for (int j = 0; j < 4; j++) {
      int row = qg0 + g * 4 + j;
      ctx[(size_t)(b * 1024 + row) * 512 + h * 64 + dg * 16 + l16] =
          (__bf16)(cacc[dg][j] * rcj[j]);
    }
  if (l16 == 0) {
#pragma unroll
    for (int j = 0; j < 4; j++) {
      int li = (b * 8 + h) * 1024 + qg0 + g * 4 + j;
      crl[li] = (lsacc[j] > 0.f) ? (Cj[j] + __log2f(lsacc[j])) : 1.0e30f;
    }
  }
}

// ---------------- attention mean over heads -> mout (barrier-free, swapped QK) ----------------
__global__ __launch_bounds__(256, 4) void k_attn_mean(const bf16_t* __restrict__ q,
                                                      const bf16_t* __restrict__ kk,
                                                      const bf16_t* __restrict__ eadjT,
                                                      const float* __restrict__ crl,
                                                      float* __restrict__ mout) {
  __shared__ bf16_t lds[4][2][2048];   // [wave][buf][4KB]
  int bid = blockIdx.x;
  int kq = bid & 7, qt = (bid >> 3) & 15, b = bid >> 7;
  int tid = threadIdx.x, wid = tid >> 6, lane = tid & 63;
  int l16 = lane & 15, g = lane >> 4;
  int qg0 = qt * 64 + wid * 16;
  int kbase = kq * 128;
  int rl = lane >> 3;
  int cb = (lane & 7) ^ rl;
  const bf16_t* ksrc = kk + (size_t)(b * 1024 + kbase) * 512;

  auto stage = [&](int t) {
    int h = t >> 2, c = t & 3;
    char* dst = (char*)&lds[wid][t & 1][0];
    const bf16_t* sp = ksrc + (size_t)(c * 32 + rl) * 512 + h * 64 + cb * 8;
#pragma unroll
    for (int i = 0; i < 4; i++)
      gload_lds16(sp + (size_t)i * 8 * 512, dst + i * 1024);
  };

  f32x4 macc[8];
#pragma unroll
  for (int kg = 0; kg < 8; kg++) macc[kg] = (f32x4){0.f, 0.f, 0.f, 0.f};

  stage(0);

  for (int h = 0; h < 8; h++) {
    const bf16_t* qp = q + (size_t)(b * 1024 + qg0 + l16) * 512 + h * 64 + 8 * g;
    bf16x8 aq0 = *(const bf16x8*)qp;
    bf16x8 aq1 = *(const bf16x8*)(qp + 32);
    float CRs = crl[(b * 8 + h) * 1024 + qg0 + l16];   // own q-row
    f32x4 negCR4 = (f32x4){-CRs, -CRs, -CRs, -CRs};
#pragma unroll
    for (int c = 0; c < 4; c++) {
      int t = h * 4 + c;
      __builtin_amdgcn_sched_barrier(0);
      if (t < 31) {
        stage(t + 1);
        __builtin_amdgcn_sched_barrier(0);
        asm volatile("s_waitcnt vmcnt(4)" ::: "memory");
      } else {
        asm volatile("s_waitcnt vmcnt(0)" ::: "memory");
      }
      __builtin_amdgcn_sched_barrier(0);
      const char* cK = (const char*)&lds[wid][t & 1][0];
#pragma unroll
      for (int cg = 0; cg < 2; cg++) {
        const char* krow = cK + ((cg * 16 + l16) << 7);
        bf16x8 k0 = *(const bf16x8*)(krow + ((g ^ (l16 & 7)) << 4));
        bf16x8 k1 = *(const bf16x8*)(krow + (((g + 4) ^ (l16 & 7)) << 4));
        __builtin_amdgcn_s_setprio(1);
        f32x4 s = mfma16(k0, aq0, negCR4);   // SWAPPED
        s = mfma16(k1, aq1, s);
        __builtin_amdgcn_s_setprio(0);
        int kg = c * 2 + cg;
#pragma unroll
        for (int j = 0; j < 4; j++)
          macc[kg][j] += exp2f(s[j]);
      }
    }
  }

  const bf16_t* erowT = eadjT + (size_t)(qg0 + l16) * 1024 + kbase + g * 16;
  bf16x8 eA0 = *(const bf16x8*)(erowT);        // group A, c' 0,1
  bf16x8 eA1 = *(const bf16x8*)(erowT + 8);    // group A, c' 2,3
  bf16x8 eB0 = *(const bf16x8*)(erowT + 64);   // group B, c' 0,1
  bf16x8 eB1 = *(const bf16x8*)(erowT + 72);   // group B, c' 2,3
  float* mrow = mout + (size_t)b * 1048576 + (size_t)(qg0 + l16) * 1024 + kbase;
#pragma unroll
  for (int kg = 0; kg < 8; kg++) {
    bf16x8 eg = (kg < 2) ? eA0 : (kg < 4) ? eA1 : (kg < 6) ? eB0 : eB1;
    f32x4 mv;
#pragma unroll
    for (int j = 0; j < 4; j++)
      mv[j] = macc[kg][j] * (float)eg[(kg & 1) * 4 + j] * 0.125f;
    *(f32x4*)(mrow + kg * 16 + g * 4) = mv;
  }
}

extern "C" void kernel_launch(void* const* d_in, const int* in_sizes, int n_in,
                              void* d_out, int out_size, void* d_ws, size_t ws_size,
                              hipStream_t stream) {
  (void)in_sizes; (void)n_in; (void)out_size; (void)ws_size;
  const float* x   = (const float*)d_in[0];
  const float* adj = (const float*)d_in[1];
  const int*   msk = (const int*)d_in[2];
  const float* Wq  = (const float*)d_in[3];
  const float* Wk  = (const float*)d_in[4];
  const float* Wv  = (const float*)d_in[5];
  const float* Wo  = (const float*)d_in[6];
  const float* W1  = (const float*)d_in[7];
  const float* b1  = (const float*)d_in[8];
  const float* W2  = (const float*)d_in[9];
  const float* b2  = (const float*)d_in[10];
  const float* g1  = (const float*)d_in[11];
  const float* be1 = (const float*)d_in[12];
  const float* g2  = (const float*)d_in[13];
  const float* be2 = (const float*)d_in[14];

  float* out  = (float*)d_out;
  float* mout = out + (size_t)8 * 1024 * 512;

  char* ws = (char*)d_ws;
  const size_t MB = 1024 * 1024;
  bf16_t* wqb = (bf16_t*)(ws);
  bf16_t* wkb = (bf16_t*)(ws + 512 * 1024);
  bf16_t* wvb = (bf16_t*)(ws + 1 * MB);
  bf16_t* wob = (bf16_t*)(ws + 3 * MB / 2);
  bf16_t* w1b = (bf16_t*)(ws + 2 * MB);
  bf16_t* w2b = (bf16_t*)(ws + 4 * MB);
  float*  crl  = (float*)(ws + 6 * MB + 256 * 1024); // 256 KB (C + log2 l)
  float*  kmax = (float*)(ws + 6 * MB + 768 * 1024); // 256 B
  bf16_t* xb   = (bf16_t*)(ws + 8 * MB);   // 8-16: x bf16; then ctx; then zb
  bf16_t* ctx  = xb;
  bf16_t* zb   = xb;
  bf16_t* qb   = (bf16_t*)(ws + 16 * MB);  // 16-24 (dead after attn_mean)
  bf16_t* kb   = (bf16_t*)(ws + 24 * MB);  // 24-32 (dead after attn_mean)
  bf16_t* vb   = (bf16_t*)(ws + 32 * MB);  // 32-40 (dead after vtrans)
  bf16_t* vT   = (bf16_t*)(ws + 40 * MB);  // 40-48 (dead after attn_ctx)
  bf16_t* gout1 = (bf16_t*)(ws + 16 * MB); // 16-32: 2x8MB bf16 (wo split-K partials)
  bf16_t* hb    = (bf16_t*)(ws + 16 * MB); // 16-48 bf16 (ffn1 -> ffn2; after resln1)
  bf16_t* gout2 = (bf16_t*)(ws + 48 * MB); // 48-64: 2x8MB bf16 (ffn2 split-K partials)
  bf16_t* eadjT = (bf16_t*)(ws + 72 * MB); // 72-74 permuted exp(adj)*mask table

  // converts + eadj prep (one launch)
  k_cvtall<<<7424, 256, 0, stream>>>(x, Wq, Wk, Wv, Wo, W1, W2, adj, msk,
                                     xb, wqb, wkb, wvb, wob, w1b, w2b, eadjT);

  // QKV: one GEMM, N=1536 (wq|wk|wv contiguous); q pre-scaled by 0.125*log2e
  k_gemm<0, 1><<<64 * 12, 256, 0, stream>>>(xb, wqb, 512, 12, nullptr, qb, 512);
  // v transpose (k-permuted) + kmax in one launch
  k_vtrans_knorm<<<1088, 256, 0, stream>>>(vb, vT, kb, kmax);

  // attention: ctx (swapped-QK register-P pipeline, MFMA row-sum) + crl, then mean
  k_attn_ctx<<<512, 512, 0, stream>>>(qb, kb, vT, eadjT, kmax, ctx, crl);
  k_attn_mean<<<1024, 256, 0, stream>>>(qb, kb, eadjT, crl, mout);

  // Wo proj (split-K x2, bf16 partials) -> gout1[2]; resid(x) + LN1 -> zb
  k_gemm<2, 2><<<2 * 64 * 4, 256, 0, stream>>>(ctx, wob, 512, 4, nullptr, gout1, 512);
  k_resln<<<2048, 256, 0, stream>>>(gout1, 2, x, nullptr, g1, be1, nullptr, zb);
  // FFN1: relu(zb @ W1^T + b1) -> hb
  k_gemm<1, 1><<<64 * 16, 256, 0, stream>>>(zb, w1b, 512, 16, b1, hb, 2048);
  // FFN2 (split-K x2, bf16 partials) -> gout2[2]; resid(zb) + LN2 -> out
  k_gemm<2, 2><<<2 * 64 * 4, 256, 0, stream>>>(hb, w2b, 2048, 4, b2, gout2, 512);
  k_resln<<<2048, 256, 0, stream>>>(gout2, 2, nullptr, zb, g2, be2, out, nullptr);
}